// Round 4
// baseline (552.251 us; speedup 1.0000x reference)
//
#include <hip/hip_runtime.h>

typedef __attribute__((ext_vector_type(8))) short short8;
typedef __attribute__((ext_vector_type(4))) float f32x4;

__device__ inline unsigned short f2b(float f) {
  unsigned int u = __builtin_bit_cast(unsigned int, f);
  u = (u + 0x7FFFu + ((u >> 16) & 1u)) >> 16;
  return (unsigned short)u;
}
__device__ inline float b2f(unsigned short s) {
  unsigned int u = ((unsigned int)s) << 16;
  return __builtin_bit_cast(float, u);
}

__device__ inline void async16(const void* g, void* l) {
  __builtin_amdgcn_global_load_lds((__attribute__((address_space(1))) void*)(g),
                                   (__attribute__((address_space(3))) void*)(l), 16, 0, 0);
}

// ---------------- x fp32 -> bf16 ----------------
__global__ void cvt_x(const float4* __restrict__ x, ushort4* __restrict__ xb, int n4) {
  int i = blockIdx.x * blockDim.x + threadIdx.x;
  int stride = gridDim.x * blockDim.x;
  for (; i < n4; i += stride) {
    float4 v = x[i];
    ushort4 o;
    o.x = f2b(v.x); o.y = f2b(v.y); o.z = f2b(v.z); o.w = f2b(v.w);
    xb[i] = o;
  }
}

// ---------------- W_qkv [768][2304] -> Wt [2304(perm s,h,d)][768] bf16 ----------------
__global__ __launch_bounds__(256) void t_wqkv(const float* __restrict__ W, unsigned short* __restrict__ Wt) {
  __shared__ float tile[32][33];
  int j0 = blockIdx.x * 32, c0 = blockIdx.y * 32;
  int tx = threadIdx.x & 31, ty = threadIdx.x >> 5;
#pragma unroll
  for (int r = 0; r < 32; r += 8)
    tile[ty + r][tx] = W[(size_t)(c0 + ty + r) * 2304 + j0 + tx];
  __syncthreads();
#pragma unroll
  for (int r = 0; r < 32; r += 8) {
    int j = j0 + ty + r;
    int h = j / 288, rem = j - h * 288;
    int d = rem / 3, s = rem - d * 3;
    int jj = s * 768 + h * 96 + d;
    Wt[(size_t)jj * 768 + c0 + tx] = f2b(tile[tx][ty + r]);
  }
}

// ---------------- W_proj [768][768] -> Wt [768][768] bf16 (transpose) ----------------
__global__ __launch_bounds__(256) void t_wproj(const float* __restrict__ W, unsigned short* __restrict__ Wt) {
  __shared__ float tile[32][33];
  int j0 = blockIdx.x * 32, c0 = blockIdx.y * 32;
  int tx = threadIdx.x & 31, ty = threadIdx.x >> 5;
#pragma unroll
  for (int r = 0; r < 32; r += 8)
    tile[ty + r][tx] = W[(size_t)(c0 + ty + r) * 768 + j0 + tx];
  __syncthreads();
#pragma unroll
  for (int r = 0; r < 32; r += 8)
    Wt[(size_t)(j0 + ty + r) * 768 + c0 + tx] = f2b(tile[tx][ty + r]);
}

// ---------------- GEMM1: qkv = xb @ Wqkv, 256x256 tile, deep-pipelined ----------------
// 8 waves (2M x 4N), BK=64, double-buffered 128 KiB LDS, counted vmcnt (never 0
// mid-loop), raw s_barrier. Scatter epilogue to Q/K/V [b][h][n][96] bf16 as before.
__global__ __launch_bounds__(512, 2) void gemm_qkv(
    const unsigned short* __restrict__ A, const unsigned short* __restrict__ Bt,
    unsigned short* __restrict__ Q, unsigned short* __restrict__ Kd, unsigned short* __restrict__ V) {
  extern __shared__ __align__(16) unsigned short smem[];  // 2 bufs x (As 16384 + Bs 16384)
  const int tid = threadIdx.x;
  const int wave = tid >> 6, lane = tid & 63;
  const int mlane = lane & 15, quad = lane >> 4;
  const int m0 = blockIdx.x * 256, n0 = blockIdx.y * 256;
  const int wm = (wave >> 2) * 128;  // 2 m-groups of 128
  const int wn = (wave & 3) * 64;    // 4 n-groups of 64

  f32x4 acc[8][4] = {};

  // stage K-step kt into buffer c: 4 A-rounds + 4 B-rounds of global_load_lds x16B
  auto stage = [&](int kt, int c) {
    const int k0 = kt * 64;
    unsigned short* As_c = smem + c * 32768;
    unsigned short* Bs_c = As_c + 16384;
#pragma unroll
    for (int i = 0; i < 4; ++i) {
      int ebase = i * 512 + (wave << 6);  // wave-uniform
      int e = ebase + lane;
      int row = e >> 3, slot = e & 7;
      async16(A + (size_t)(m0 + row) * 768 + k0 + slot * 8, As_c + (size_t)ebase * 8);
      async16(Bt + (size_t)(n0 + row) * 768 + k0 + slot * 8, Bs_c + (size_t)ebase * 8);
    }
  };

  // prologue: fill both buffers, wait for buf0 (keep buf1's 8 loads in flight)
  stage(0, 0);
  stage(1, 1);
  asm volatile("s_waitcnt vmcnt(8)" ::: "memory");
  __builtin_amdgcn_s_barrier();

#pragma unroll 1
  for (int t = 0; t < 12; ++t) {
    const int c = t & 1;
    const unsigned short* As_c = smem + c * 32768;
    const unsigned short* Bs_c = As_c + 16384;

    // read all fragments for this K-step into registers
    short8 af[2][2][4];  // [mh][kk][f]
    short8 bf[2][4];     // [kk][j]
#pragma unroll
    for (int mh = 0; mh < 2; ++mh)
#pragma unroll
      for (int kk = 0; kk < 2; ++kk)
#pragma unroll
        for (int f = 0; f < 4; ++f)
          af[mh][kk][f] = *(const short8*)&As_c[(wm + mh * 64 + f * 16 + mlane) * 64 + kk * 32 + quad * 8];
#pragma unroll
    for (int kk = 0; kk < 2; ++kk)
#pragma unroll
      for (int j = 0; j < 4; ++j)
        bf[kk][j] = *(const short8*)&Bs_c[(wn + j * 16 + mlane) * 64 + kk * 32 + quad * 8];

    if (t < 10) {
      // WAR fence: all waves must finish reading buf c before we overwrite it
      asm volatile("s_waitcnt lgkmcnt(0)" ::: "memory");
      __builtin_amdgcn_sched_barrier(0);
      __builtin_amdgcn_s_barrier();
      stage(t + 2, c);  // 8 more loads in flight (16 outstanding)
    }

    __builtin_amdgcn_s_setprio(1);
#pragma unroll
    for (int kk = 0; kk < 2; ++kk)
#pragma unroll
      for (int mh = 0; mh < 2; ++mh)
#pragma unroll
        for (int f = 0; f < 4; ++f)
#pragma unroll
          for (int j = 0; j < 4; ++j)
            acc[mh * 4 + f][j] =
                __builtin_amdgcn_mfma_f32_16x16x32_bf16(af[mh][kk][f], bf[kk][j], acc[mh * 4 + f][j], 0, 0, 0);
    __builtin_amdgcn_s_setprio(0);

    if (t < 10) {
      asm volatile("s_waitcnt vmcnt(8)" ::: "memory");  // t+1's loads landed
      __builtin_amdgcn_s_barrier();
    } else if (t == 10) {
      asm volatile("s_waitcnt vmcnt(0)" ::: "memory");  // drain t=11's loads
      __builtin_amdgcn_s_barrier();
    }
  }

  // scatter epilogue (unchanged math, per-wave 8x4 fragments)
  const int bb = m0 >> 12;
  const int nb = (m0 & 4095) + wm + quad * 4;
#pragma unroll
  for (int j = 0; j < 4; ++j) {
    int jj = n0 + wn + j * 16 + mlane;
    int s = jj / 768;
    int hd = jj - s * 768;
    int h = hd / 96;
    int d = hd - h * 96;
    unsigned short* dst = (s == 0) ? Q : (s == 1) ? Kd : V;
    size_t colbase = ((size_t)(bb * 8 + h) * 4096) * 96 + d;
#pragma unroll
    for (int mf = 0; mf < 8; ++mf) {
      int n = nb + (mf >> 2) * 64 + (mf & 3) * 16;
#pragma unroll
      for (int r = 0; r < 4; ++r)
        dst[colbase + (size_t)(n + r) * 96] = f2b(acc[mf][j][r]);
    }
  }
}

// ---------------- attn split-K partial: Spart[bh][chunk][96][96] fp32 ----------------
// sum-of-squares over n for Q and K is fused into the staging loop (each staging
// thread owns d-columns 2c, 2c+1 and sees every (n, d) element exactly once).
__global__ __launch_bounds__(256) void attn_partial(
    const unsigned short* __restrict__ Q, const unsigned short* __restrict__ Kd,
    float* __restrict__ Spart, float* __restrict__ sq, float* __restrict__ sk) {
  int chunk = blockIdx.x;  // 16 chunks of 256 rows
  int bh = blockIdx.y;
  __shared__ __align__(16) unsigned short QT[96 * 72];
  __shared__ __align__(16) unsigned short KT[96 * 72];
  int t = threadIdx.x;
  int wave = t >> 6, lane = t & 63, mlane = lane & 15, quad = lane >> 4;
  int wrow = (wave >> 1) * 48, wcol = (wave & 1) * 48;
  f32x4 acc[3][3] = {};
  const unsigned int* qp = (const unsigned int*)(Q + (size_t)bh * 4096 * 96);
  const unsigned int* kp = (const unsigned int*)(Kd + (size_t)bh * 4096 * 96);
  int c = t % 48, rg = t / 48;
  int nbeg = chunk * 256;
  float aq0 = 0.f, aq1 = 0.f, ak0 = 0.f, ak1 = 0.f;
  for (int n0 = nbeg; n0 < nbeg + 256; n0 += 64) {
    __syncthreads();
    if (rg < 5) {
      for (int n = rg; n < 64; n += 5) {
        unsigned int qv = qp[(size_t)(n0 + n) * 48 + c];
        unsigned int kv = kp[(size_t)(n0 + n) * 48 + c];
        QT[(2 * c) * 72 + n] = (unsigned short)(qv & 0xffff);
        QT[(2 * c + 1) * 72 + n] = (unsigned short)(qv >> 16);
        KT[(2 * c) * 72 + n] = (unsigned short)(kv & 0xffff);
        KT[(2 * c + 1) * 72 + n] = (unsigned short)(kv >> 16);
        float q0 = b2f((unsigned short)(qv & 0xffff)), q1 = b2f((unsigned short)(qv >> 16));
        float k0 = b2f((unsigned short)(kv & 0xffff)), k1 = b2f((unsigned short)(kv >> 16));
        aq0 += q0 * q0; aq1 += q1 * q1; ak0 += k0 * k0; ak1 += k1 * k1;
      }
    }
    __syncthreads();
#pragma unroll
    for (int kk = 0; kk < 64; kk += 32) {
      short8 a[3], bf[3];
#pragma unroll
      for (int f = 0; f < 3; ++f)
        a[f] = *(const short8*)&QT[(wrow + f * 16 + mlane) * 72 + kk + quad * 8];
#pragma unroll
      for (int f = 0; f < 3; ++f)
        bf[f] = *(const short8*)&KT[(wcol + f * 16 + mlane) * 72 + kk + quad * 8];
#pragma unroll
      for (int i = 0; i < 3; ++i)
#pragma unroll
        for (int j = 0; j < 3; ++j)
          acc[i][j] = __builtin_amdgcn_mfma_f32_16x16x32_bf16(a[i], bf[j], acc[i][j], 0, 0, 0);
    }
  }
  if (rg < 5) {
    atomicAdd(&sq[bh * 96 + 2 * c], aq0);
    atomicAdd(&sq[bh * 96 + 2 * c + 1], aq1);
    atomicAdd(&sk[bh * 96 + 2 * c], ak0);
    atomicAdd(&sk[bh * 96 + 2 * c + 1], ak1);
  }
  float* dst = Spart + ((size_t)bh * 16 + chunk) * 9216;
#pragma unroll
  for (int i = 0; i < 3; ++i)
#pragma unroll
    for (int j = 0; j < 3; ++j)
#pragma unroll
      for (int r = 0; r < 4; ++r)
        dst[(wrow + i * 16 + quad * 4 + r) * 96 + wcol + j * 16 + mlane] = acc[i][j][r];
}

// ---------------- finalize: sum partials, normalize, softmax, write P bf16 ----------------
__global__ __launch_bounds__(256) void attn_finalize(
    const float* __restrict__ Spart, const float* __restrict__ sq,
    const float* __restrict__ sk, const float* __restrict__ temp,
    unsigned short* __restrict__ P) {
  int bh = blockIdx.x, h = bh & 7;
  __shared__ float S[9216];
  __shared__ float rk[96], rq[96];
  int t = threadIdx.x;
  const float* base = Spart + (size_t)bh * 16 * 9216;
  if (t < 96) {
    rk[t] = rsqrtf(sk[bh * 96 + t]);
    rq[t] = rsqrtf(sq[bh * 96 + t]) * temp[h];
  }
  __syncthreads();
  for (int i = t; i < 9216; i += 256) {
    float s = 0.f;
#pragma unroll
    for (int c2 = 0; c2 < 16; ++c2) s += base[(size_t)c2 * 9216 + i];
    int d = i / 96, e = i - d * 96;
    S[i] = s * rq[d] * rk[e];
  }
  __syncthreads();
  if (t < 96) {
    int d = t;
    float mx = -1e30f;
    for (int e = 0; e < 96; ++e) mx = fmaxf(mx, S[d * 96 + e]);
    float sum = 0.f;
    for (int e = 0; e < 96; ++e) {
      float v = expf(S[d * 96 + e] - mx);
      S[d * 96 + e] = v;
      sum += v;
    }
    float inv = 1.0f / sum;
    for (int e = 0; e < 96; ++e)
      P[(size_t)bh * 9216 + d * 96 + e] = f2b(S[d * 96 + e] * inv);
  }
}

// ---------------- y = V @ P^T per (b,h): y[b][n][h*96+d] bf16 ----------------
__global__ __launch_bounds__(256) void gemm_pv(
    const unsigned short* __restrict__ V, const unsigned short* __restrict__ P,
    unsigned short* __restrict__ y) {
  int bh = blockIdx.y;
  int b = bh >> 3, h = bh & 7;
  int m0 = blockIdx.x * 128;
  int t = threadIdx.x, wave = t >> 6, lane = t & 63, mlane = lane & 15, quad = lane >> 4;
  const unsigned short* Vb = V + (size_t)bh * 4096 * 96;
  const unsigned short* Pb = P + (size_t)bh * 9216;
  f32x4 acc[2][6] = {};
#pragma unroll
  for (int kk = 0; kk < 96; kk += 32) {
    short8 a[2], bfr[6];
#pragma unroll
    for (int i = 0; i < 2; ++i)
      a[i] = *(const short8*)&Vb[(size_t)(m0 + wave * 32 + i * 16 + mlane) * 96 + kk + quad * 8];
#pragma unroll
    for (int j = 0; j < 6; ++j)
      bfr[j] = *(const short8*)&Pb[(j * 16 + mlane) * 96 + kk + quad * 8];
#pragma unroll
    for (int i = 0; i < 2; ++i)
#pragma unroll
      for (int j = 0; j < 6; ++j)
        acc[i][j] = __builtin_amdgcn_mfma_f32_16x16x32_bf16(a[i], bfr[j], acc[i][j], 0, 0, 0);
  }
#pragma unroll
  for (int i = 0; i < 2; ++i) {
    int n = m0 + wave * 32 + i * 16 + quad * 4;
#pragma unroll
    for (int j = 0; j < 6; ++j) {
      int d = j * 16 + mlane;
#pragma unroll
      for (int r = 0; r < 4; ++r)
        y[((size_t)b * 4096 + n + r) * 768 + h * 96 + d] = f2b(acc[i][j][r]);
    }
  }
}

// ---------------- proj: out = y @ Wp + bias (fp32 out) ----------------
__global__ __launch_bounds__(256) void gemm_proj(
    const unsigned short* __restrict__ A, const unsigned short* __restrict__ Bt,
    const float* __restrict__ bias, float* __restrict__ out) {
  __shared__ __align__(16) unsigned short As[128 * 64];
  __shared__ __align__(16) unsigned short Bs[128 * 64];
  const int tid = threadIdx.x;
  const int wave = tid >> 6, lane = tid & 63;
  const int mlane = lane & 15, quad = lane >> 4;
  const int m0 = blockIdx.x * 128, n0 = blockIdx.y * 128;
  const int wm = (wave >> 1) * 64, wn = (wave & 1) * 64;
  f32x4 acc[4][4] = {};
  for (int k0 = 0; k0 < 768; k0 += 64) {
    __syncthreads();
#pragma unroll
    for (int t = 0; t < 4; ++t) {
      int ebase = t * 256 + (wave << 6);
      int e = ebase + lane;
      int row = e >> 3, c8 = e & 7;
      async16(A + (size_t)(m0 + row) * 768 + k0 + c8 * 8, As + ebase * 8);
      async16(Bt + (size_t)(n0 + row) * 768 + k0 + c8 * 8, Bs + ebase * 8);
    }
    __syncthreads();
#pragma unroll
    for (int kk = 0; kk < 64; kk += 32) {
      short8 a[4], b[4];
#pragma unroll
      for (int f = 0; f < 4; ++f)
        a[f] = *(const short8*)&As[(wm + f * 16 + mlane) * 64 + kk + quad * 8];
#pragma unroll
      for (int f = 0; f < 4; ++f)
        b[f] = *(const short8*)&Bs[(wn + f * 16 + mlane) * 64 + kk + quad * 8];
#pragma unroll
      for (int i = 0; i < 4; ++i)
#pragma unroll
        for (int j = 0; j < 4; ++j)
          acc[i][j] = __builtin_amdgcn_mfma_f32_16x16x32_bf16(a[i], b[j], acc[i][j], 0, 0, 0);
    }
  }
#pragma unroll
  for (int fn = 0; fn < 4; ++fn) {
    int col = n0 + wn + fn * 16 + mlane;
    float bv = bias[col];
#pragma unroll
    for (int fm = 0; fm < 4; ++fm) {
      int m = m0 + wm + fm * 16 + quad * 4;
#pragma unroll
      for (int r = 0; r < 4; ++r)
        out[(size_t)(m + r) * 768 + col] = acc[fm][fn][r] + bv;
    }
  }
}

extern "C" void kernel_launch(void* const* d_in, const int* in_sizes, int n_in,
                              void* d_out, int out_size, void* d_ws, size_t ws_size,
                              hipStream_t stream) {
  const float* x = (const float*)d_in[0];
  const float* Wqkv = (const float*)d_in[1];
  const float* Wproj = (const float*)d_in[2];
  const float* bias = (const float*)d_in[3];
  const float* temp = (const float*)d_in[4];
  float* out = (float*)d_out;

  char* ws = (char*)d_ws;
  size_t off = 0;
  auto alloc = [&](size_t bytes) -> void* {
    void* p = ws + off;
    off += (bytes + 255) & ~(size_t)255;
    return p;
  };
  unsigned short* xb = (unsigned short*)alloc(32768ull * 768 * 2);  // reused as y after gemm_qkv
  unsigned short* Wtq = (unsigned short*)alloc(2304ull * 768 * 2);
  unsigned short* Wtp = (unsigned short*)alloc(768ull * 768 * 2);
  unsigned short* Q = (unsigned short*)alloc(64ull * 4096 * 96 * 2);
  unsigned short* Kd = (unsigned short*)alloc(64ull * 4096 * 96 * 2);
  unsigned short* V = (unsigned short*)alloc(64ull * 4096 * 96 * 2);
  float* sq = (float*)alloc(64 * 96 * 4);
  float* sk = (float*)alloc(64 * 96 * 4);
  unsigned short* P = (unsigned short*)alloc(64ull * 9216 * 2);
  (void)off; (void)ws_size; (void)in_sizes; (void)n_in; (void)out_size;

  // Spart (64*16*9216 fp32 = 37.75 MB) staged in d_out (100 MB), which is
  // only written by gemm_proj at the very end — stream-ordered, no race.
  float* Spart = out;

  // one-time: allow 128 KiB dynamic LDS for the 256x256 deep-pipelined GEMM
  static bool attr_set = false;
  if (!attr_set) {
    hipFuncSetAttribute((const void*)gemm_qkv, hipFuncAttributeMaxDynamicSharedMemorySize, 131072);
    attr_set = true;
  }

  cvt_x<<<4096, 256, 0, stream>>>((const float4*)x, (ushort4*)xb, 32768 * 768 / 4);
  t_wqkv<<<dim3(72, 24), 256, 0, stream>>>(Wqkv, Wtq);
  t_wproj<<<dim3(24, 24), 256, 0, stream>>>(Wproj, Wtp);
  hipMemsetAsync(sq, 0, 64 * 96 * 4, stream);
  hipMemsetAsync(sk, 0, 64 * 96 * 4, stream);
  gemm_qkv<<<dim3(128, 9), 512, 131072, stream>>>(xb, Wtq, Q, Kd, V);
  attn_partial<<<dim3(16, 64), 256, 0, stream>>>(Q, Kd, Spart, sq, sk);
  attn_finalize<<<64, 256, 0, stream>>>(Spart, sq, sk, temp, P);
  gemm_pv<<<dim3(32, 64), 256, 0, stream>>>(V, P, xb /*y*/);
  gemm_proj<<<dim3(256, 6), 256, 0, stream>>>(xb /*y*/, Wtp, bias, out);
}

// Round 6
// 490.014 us; speedup vs baseline: 1.1270x; 1.1270x over previous
//
#include <hip/hip_runtime.h>

typedef __attribute__((ext_vector_type(8))) short short8;
typedef __attribute__((ext_vector_type(4))) float f32x4;

__device__ inline unsigned short f2b(float f) {
  unsigned int u = __builtin_bit_cast(unsigned int, f);
  u = (u + 0x7FFFu + ((u >> 16) & 1u)) >> 16;
  return (unsigned short)u;
}
__device__ inline float b2f(unsigned short s) {
  unsigned int u = ((unsigned int)s) << 16;
  return __builtin_bit_cast(float, u);
}

__device__ inline void async16(const void* g, void* l) {
  __builtin_amdgcn_global_load_lds((__attribute__((address_space(1))) void*)(g),
                                   (__attribute__((address_space(3))) void*)(l), 16, 0, 0);
}

// ---------------- x fp32 -> bf16 ----------------
__global__ void cvt_x(const float4* __restrict__ x, ushort4* __restrict__ xb, int n4) {
  int i = blockIdx.x * blockDim.x + threadIdx.x;
  int stride = gridDim.x * blockDim.x;
  for (; i < n4; i += stride) {
    float4 v = x[i];
    ushort4 o;
    o.x = f2b(v.x); o.y = f2b(v.y); o.z = f2b(v.z); o.w = f2b(v.w);
    xb[i] = o;
  }
}

// ---------------- W_qkv [768][2304] -> Wt [2304(perm s,h,d)][768] bf16 ----------------
__global__ __launch_bounds__(256) void t_wqkv(const float* __restrict__ W, unsigned short* __restrict__ Wt) {
  __shared__ float tile[32][33];
  int j0 = blockIdx.x * 32, c0 = blockIdx.y * 32;
  int tx = threadIdx.x & 31, ty = threadIdx.x >> 5;
#pragma unroll
  for (int r = 0; r < 32; r += 8)
    tile[ty + r][tx] = W[(size_t)(c0 + ty + r) * 2304 + j0 + tx];
  __syncthreads();
#pragma unroll
  for (int r = 0; r < 32; r += 8) {
    int j = j0 + ty + r;
    int h = j / 288, rem = j - h * 288;
    int d = rem / 3, s = rem - d * 3;
    int jj = s * 768 + h * 96 + d;
    Wt[(size_t)jj * 768 + c0 + tx] = f2b(tile[tx][ty + r]);
  }
}

// ---------------- W_proj [768][768] -> Wt [768][768] bf16 (transpose) ----------------
__global__ __launch_bounds__(256) void t_wproj(const float* __restrict__ W, unsigned short* __restrict__ Wt) {
  __shared__ float tile[32][33];
  int j0 = blockIdx.x * 32, c0 = blockIdx.y * 32;
  int tx = threadIdx.x & 31, ty = threadIdx.x >> 5;
#pragma unroll
  for (int r = 0; r < 32; r += 8)
    tile[ty + r][tx] = W[(size_t)(c0 + ty + r) * 768 + j0 + tx];
  __syncthreads();
#pragma unroll
  for (int r = 0; r < 32; r += 8)
    Wt[(size_t)(j0 + ty + r) * 768 + c0 + tx] = f2b(tile[tx][ty + r]);
}

// ---------------- GEMM1: qkv = xb @ Wqkv, 256x256 tile, 4-phase interleaved ----------------
// 8 waves (2M x 4N), BK=64, double-buffered 128 KiB LDS with T2 XOR-swizzle
// (inverse-swizzled global source + swizzled ds_read; LDS dest linear).
// Per K-tile: 4 phases {ds_reads -> lgkmcnt(0) -> setprio+16 MFMA -> barrier};
// phase 4 stages K-tile t+2 under its MFMA and closes with counted vmcnt(8).
__global__ __launch_bounds__(512, 2) void gemm_qkv(
    const unsigned short* __restrict__ A, const unsigned short* __restrict__ Bt,
    unsigned short* __restrict__ Q, unsigned short* __restrict__ Kd, unsigned short* __restrict__ V) {
  extern __shared__ __align__(16) unsigned short smem[];  // [2 bufs][4 halves][8192 elems]
  const int tid = threadIdx.x;
  const int wave = tid >> 6, lane = tid & 63;
  const int mlane = lane & 15, quad = lane >> 4;
  const int m0 = blockIdx.x * 256, n0 = blockIdx.y * 256;
  const int ah = wave >> 2;        // A-half (0/1): rows [ah*128, ah*128+128)
  const int wm = ah * 128;
  const int wn = (wave & 3) * 64;  // output col group
  const int bh = wn >> 7;          // B-half (0/1)
  const int bl = wn & 64;          // local row base within B-half

  f32x4 acc[8][4] = {};  // [mh*4+f][j]

  // stage K-tile kt into buffer c (4 halves x 2 loads/thread = 8 global_load_lds)
  auto stage = [&](int kt, int c) {
    const int k0 = kt * 64;
#pragma unroll
    for (int h = 0; h < 4; ++h) {
      const unsigned short* src = (h < 2) ? A : Bt;
      const int rbase = ((h < 2) ? m0 : n0) + (h & 1) * 128;
      unsigned short* ldsbase = smem + c * 32768 + h * 8192;
#pragma unroll
      for (int i = 0; i < 2; ++i) {
        int ebase = i * 512 + (wave << 6);  // wave-uniform LDS dest
        int e = ebase + lane;
        int row = e >> 3;
        int slot = (e & 7) ^ (row & 7);  // inverse swizzle on global source
        async16(src + (size_t)(rbase + row) * 768 + k0 + slot * 8, ldsbase + ebase * 8);
      }
    }
  };

  // swizzled fragment reads (within a 128x64 half)
  auto rdA = [&](const unsigned short* base, int mh, int kk, int f) -> short8 {
    int r = mh * 64 + f * 16 + mlane;
    return *(const short8*)&base[r * 64 + ((kk * 32 + quad * 8) ^ ((r & 7) << 3))];
  };
  auto rdB = [&](const unsigned short* base, int kk, int j) -> short8 {
    int r = bl + j * 16 + mlane;
    return *(const short8*)&base[r * 64 + ((kk * 32 + quad * 8) ^ ((r & 7) << 3))];
  };

  // prologue: fill both buffers; wait K-tile 0 (keep tile 1's 8 loads in flight)
  stage(0, 0);
  stage(1, 1);
  asm volatile("s_waitcnt vmcnt(8)" ::: "memory");
  __builtin_amdgcn_sched_barrier(0);
  __builtin_amdgcn_s_barrier();

#pragma unroll 1
  for (int t = 0; t < 12; ++t) {
    const int c = t & 1;
    const unsigned short* Abase = smem + c * 32768 + ah * 8192;
    const unsigned short* Bbase = smem + c * 32768 + 16384 + bh * 8192;
    short8 a0[4], a1[4], b0[4], b1[4];

    // ---- Phase 1: read B[kk0], A[mh0,kk0]; MFMA (mh0, kk0) ----
#pragma unroll
    for (int j = 0; j < 4; ++j) b0[j] = rdB(Bbase, 0, j);
#pragma unroll
    for (int f = 0; f < 4; ++f) a0[f] = rdA(Abase, 0, 0, f);
    asm volatile("s_waitcnt lgkmcnt(0)" ::: "memory");
    __builtin_amdgcn_sched_barrier(0);
    __builtin_amdgcn_s_setprio(1);
#pragma unroll
    for (int f = 0; f < 4; ++f)
#pragma unroll
      for (int j = 0; j < 4; ++j)
        acc[f][j] = __builtin_amdgcn_mfma_f32_16x16x32_bf16(a0[f], b0[j], acc[f][j], 0, 0, 0);
    __builtin_amdgcn_s_setprio(0);
    __builtin_amdgcn_s_barrier();

    // ---- Phase 2: read A[mh1,kk0], B[kk1]; MFMA (mh1, kk0) ----
#pragma unroll
    for (int f = 0; f < 4; ++f) a1[f] = rdA(Abase, 1, 0, f);
#pragma unroll
    for (int j = 0; j < 4; ++j) b1[j] = rdB(Bbase, 1, j);
    asm volatile("s_waitcnt lgkmcnt(0)" ::: "memory");
    __builtin_amdgcn_sched_barrier(0);
    __builtin_amdgcn_s_setprio(1);
#pragma unroll
    for (int f = 0; f < 4; ++f)
#pragma unroll
      for (int j = 0; j < 4; ++j)
        acc[4 + f][j] = __builtin_amdgcn_mfma_f32_16x16x32_bf16(a1[f], b0[j], acc[4 + f][j], 0, 0, 0);
    __builtin_amdgcn_s_setprio(0);
    __builtin_amdgcn_s_barrier();

    // ---- Phase 3: read A[mh0,kk1], A[mh1,kk1]; MFMA (mh0, kk1) ----
#pragma unroll
    for (int f = 0; f < 4; ++f) a0[f] = rdA(Abase, 0, 1, f);
#pragma unroll
    for (int f = 0; f < 4; ++f) a1[f] = rdA(Abase, 1, 1, f);
    asm volatile("s_waitcnt lgkmcnt(0)" ::: "memory");  // all 24 buf-c reads of this wave done
    __builtin_amdgcn_sched_barrier(0);
    __builtin_amdgcn_s_setprio(1);
#pragma unroll
    for (int f = 0; f < 4; ++f)
#pragma unroll
      for (int j = 0; j < 4; ++j)
        acc[f][j] = __builtin_amdgcn_mfma_f32_16x16x32_bf16(a0[f], b1[j], acc[f][j], 0, 0, 0);
    __builtin_amdgcn_s_setprio(0);
    __builtin_amdgcn_s_barrier();  // WAR fence: all waves done reading buf c

    // ---- Phase 4: stage t+2 into freed buf c; MFMA (mh1, kk1); counted vmcnt ----
    if (t < 10) stage(t + 2, c);
    __builtin_amdgcn_s_setprio(1);
#pragma unroll
    for (int f = 0; f < 4; ++f)
#pragma unroll
      for (int j = 0; j < 4; ++j)
        acc[4 + f][j] = __builtin_amdgcn_mfma_f32_16x16x32_bf16(a1[f], b1[j], acc[4 + f][j], 0, 0, 0);
    __builtin_amdgcn_s_setprio(0);
    if (t < 10) {
      asm volatile("s_waitcnt vmcnt(8)" ::: "memory");  // t+1's loads landed; t+2's stay in flight
      __builtin_amdgcn_sched_barrier(0);
      __builtin_amdgcn_s_barrier();
    } else if (t == 10) {
      asm volatile("s_waitcnt vmcnt(0)" ::: "memory");  // drain t=11's loads
      __builtin_amdgcn_sched_barrier(0);
      __builtin_amdgcn_s_barrier();
    }
  }

  // ---- scatter epilogue: j-innermost so the 4x32B bursts per (n) are contiguous ----
  const int bb = m0 >> 12;
  const int nbase = (m0 & 4095) + wm + quad * 4;
  unsigned short* dstp[4];
  size_t cb[4];
#pragma unroll
  for (int j = 0; j < 4; ++j) {
    int jj = n0 + wn + j * 16 + mlane;
    int s = (jj >= 1536) ? 2 : (jj >= 768) ? 1 : 0;
    int hd = jj - s * 768;
    int h = hd / 96;
    int d = hd - h * 96;
    dstp[j] = (s == 0) ? Q : (s == 1) ? Kd : V;
    cb[j] = ((size_t)(bb * 8 + h) * 4096) * 96 + d;
  }
#pragma unroll
  for (int mf = 0; mf < 8; ++mf) {
    int n = nbase + (mf >> 2) * 64 + (mf & 3) * 16;
#pragma unroll
    for (int r = 0; r < 4; ++r) {
#pragma unroll
      for (int j = 0; j < 4; ++j)
        dstp[j][cb[j] + (size_t)(n + r) * 96] = f2b(acc[mf][j][r]);
    }
  }
}

// ---------------- attn split-K partial: Spart[bh][chunk][96][96] fp32 ----------------
// sum-of-squares over n for Q and K is fused into the staging loop (each staging
// thread owns d-columns 2c, 2c+1 and sees every (n, d) element exactly once).
__global__ __launch_bounds__(256) void attn_partial(
    const unsigned short* __restrict__ Q, const unsigned short* __restrict__ Kd,
    float* __restrict__ Spart, float* __restrict__ sq, float* __restrict__ sk) {
  int chunk = blockIdx.x;  // 16 chunks of 256 rows
  int bh = blockIdx.y;
  __shared__ __align__(16) unsigned short QT[96 * 72];
  __shared__ __align__(16) unsigned short KT[96 * 72];
  int t = threadIdx.x;
  int wave = t >> 6, lane = t & 63, mlane = lane & 15, quad = lane >> 4;
  int wrow = (wave >> 1) * 48, wcol = (wave & 1) * 48;
  f32x4 acc[3][3] = {};
  const unsigned int* qp = (const unsigned int*)(Q + (size_t)bh * 4096 * 96);
  const unsigned int* kp = (const unsigned int*)(Kd + (size_t)bh * 4096 * 96);
  int c = t % 48, rg = t / 48;
  int nbeg = chunk * 256;
  float aq0 = 0.f, aq1 = 0.f, ak0 = 0.f, ak1 = 0.f;
  for (int n0 = nbeg; n0 < nbeg + 256; n0 += 64) {
    __syncthreads();
    if (rg < 5) {
      for (int n = rg; n < 64; n += 5) {
        unsigned int qv = qp[(size_t)(n0 + n) * 48 + c];
        unsigned int kv = kp[(size_t)(n0 + n) * 48 + c];
        QT[(2 * c) * 72 + n] = (unsigned short)(qv & 0xffff);
        QT[(2 * c + 1) * 72 + n] = (unsigned short)(qv >> 16);
        KT[(2 * c) * 72 + n] = (unsigned short)(kv & 0xffff);
        KT[(2 * c + 1) * 72 + n] = (unsigned short)(kv >> 16);
        float q0 = b2f((unsigned short)(qv & 0xffff)), q1 = b2f((unsigned short)(qv >> 16));
        float k0 = b2f((unsigned short)(kv & 0xffff)), k1 = b2f((unsigned short)(kv >> 16));
        aq0 += q0 * q0; aq1 += q1 * q1; ak0 += k0 * k0; ak1 += k1 * k1;
      }
    }
    __syncthreads();
#pragma unroll
    for (int kk = 0; kk < 64; kk += 32) {
      short8 a[3], bf[3];
#pragma unroll
      for (int f = 0; f < 3; ++f)
        a[f] = *(const short8*)&QT[(wrow + f * 16 + mlane) * 72 + kk + quad * 8];
#pragma unroll
      for (int f = 0; f < 3; ++f)
        bf[f] = *(const short8*)&KT[(wcol + f * 16 + mlane) * 72 + kk + quad * 8];
#pragma unroll
      for (int i = 0; i < 3; ++i)
#pragma unroll
        for (int j = 0; j < 3; ++j)
          acc[i][j] = __builtin_amdgcn_mfma_f32_16x16x32_bf16(a[i], bf[j], acc[i][j], 0, 0, 0);
    }
  }
  if (rg < 5) {
    atomicAdd(&sq[bh * 96 + 2 * c], aq0);
    atomicAdd(&sq[bh * 96 + 2 * c + 1], aq1);
    atomicAdd(&sk[bh * 96 + 2 * c], ak0);
    atomicAdd(&sk[bh * 96 + 2 * c + 1], ak1);
  }
  float* dst = Spart + ((size_t)bh * 16 + chunk) * 9216;
#pragma unroll
  for (int i = 0; i < 3; ++i)
#pragma unroll
    for (int j = 0; j < 3; ++j)
#pragma unroll
      for (int r = 0; r < 4; ++r)
        dst[(wrow + i * 16 + quad * 4 + r) * 96 + wcol + j * 16 + mlane] = acc[i][j][r];
}

// ---------------- finalize: sum partials, normalize, softmax, write P bf16 ----------------
__global__ __launch_bounds__(256) void attn_finalize(
    const float* __restrict__ Spart, const float* __restrict__ sq,
    const float* __restrict__ sk, const float* __restrict__ temp,
    unsigned short* __restrict__ P) {
  int bh = blockIdx.x, h = bh & 7;
  __shared__ float S[9216];
  __shared__ float rk[96], rq[96];
  int t = threadIdx.x;
  const float* base = Spart + (size_t)bh * 16 * 9216;
  if (t < 96) {
    rk[t] = rsqrtf(sk[bh * 96 + t]);
    rq[t] = rsqrtf(sq[bh * 96 + t]) * temp[h];
  }
  __syncthreads();
  for (int i = t; i < 9216; i += 256) {
    float s = 0.f;
#pragma unroll
    for (int c2 = 0; c2 < 16; ++c2) s += base[(size_t)c2 * 9216 + i];
    int d = i / 96, e = i - d * 96;
    S[i] = s * rq[d] * rk[e];
  }
  __syncthreads();
  if (t < 96) {
    int d = t;
    float mx = -1e30f;
    for (int e = 0; e < 96; ++e) mx = fmaxf(mx, S[d * 96 + e]);
    float sum = 0.f;
    for (int e = 0; e < 96; ++e) {
      float v = expf(S[d * 96 + e] - mx);
      S[d * 96 + e] = v;
      sum += v;
    }
    float inv = 1.0f / sum;
    for (int e = 0; e < 96; ++e)
      P[(size_t)bh * 9216 + d * 96 + e] = f2b(S[d * 96 + e] * inv);
  }
}

// ---------------- y = V @ P^T per (b,h): y[b][n][h*96+d] bf16 ----------------
__global__ __launch_bounds__(256) void gemm_pv(
    const unsigned short* __restrict__ V, const unsigned short* __restrict__ P,
    unsigned short* __restrict__ y) {
  int bh = blockIdx.y;
  int b = bh >> 3, h = bh & 7;
  int m0 = blockIdx.x * 128;
  int t = threadIdx.x, wave = t >> 6, lane = t & 63, mlane = lane & 15, quad = lane >> 4;
  const unsigned short* Vb = V + (size_t)bh * 4096 * 96;
  const unsigned short* Pb = P + (size_t)bh * 9216;
  f32x4 acc[2][6] = {};
#pragma unroll
  for (int kk = 0; kk < 96; kk += 32) {
    short8 a[2], bfr[6];
#pragma unroll
    for (int i = 0; i < 2; ++i)
      a[i] = *(const short8*)&Vb[(size_t)(m0 + wave * 32 + i * 16 + mlane) * 96 + kk + quad * 8];
#pragma unroll
    for (int j = 0; j < 6; ++j)
      bfr[j] = *(const short8*)&Pb[(j * 16 + mlane) * 96 + kk + quad * 8];
#pragma unroll
    for (int i = 0; i < 2; ++i)
#pragma unroll
      for (int j = 0; j < 6; ++j)
        acc[i][j] = __builtin_amdgcn_mfma_f32_16x16x32_bf16(a[i], bfr[j], acc[i][j], 0, 0, 0);
  }
#pragma unroll
  for (int i = 0; i < 2; ++i) {
    int n = m0 + wave * 32 + i * 16 + quad * 4;
#pragma unroll
    for (int j = 0; j < 6; ++j) {
      int d = j * 16 + mlane;
#pragma unroll
      for (int r = 0; r < 4; ++r)
        y[((size_t)b * 4096 + n + r) * 768 + h * 96 + d] = f2b(acc[i][j][r]);
    }
  }
}

// ---------------- proj: out = y @ Wp + bias (fp32 out) ----------------
__global__ __launch_bounds__(256) void gemm_proj(
    const unsigned short* __restrict__ A, const unsigned short* __restrict__ Bt,
    const float* __restrict__ bias, float* __restrict__ out) {
  __shared__ __align__(16) unsigned short As[128 * 64];
  __shared__ __align__(16) unsigned short Bs[128 * 64];
  const int tid = threadIdx.x;
  const int wave = tid >> 6, lane = tid & 63;
  const int mlane = lane & 15, quad = lane >> 4;
  const int m0 = blockIdx.x * 128, n0 = blockIdx.y * 128;
  const int wm = (wave >> 1) * 64, wn = (wave & 1) * 64;
  f32x4 acc[4][4] = {};
  for (int k0 = 0; k0 < 768; k0 += 64) {
    __syncthreads();
#pragma unroll
    for (int t = 0; t < 4; ++t) {
      int ebase = t * 256 + (wave << 6);
      int e = ebase + lane;
      int row = e >> 3, c8 = e & 7;
      async16(A + (size_t)(m0 + row) * 768 + k0 + c8 * 8, As + ebase * 8);
      async16(Bt + (size_t)(n0 + row) * 768 + k0 + c8 * 8, Bs + ebase * 8);
    }
    __syncthreads();
#pragma unroll
    for (int kk = 0; kk < 64; kk += 32) {
      short8 a[4], b[4];
#pragma unroll
      for (int f = 0; f < 4; ++f)
        a[f] = *(const short8*)&As[(wm + f * 16 + mlane) * 64 + kk + quad * 8];
#pragma unroll
      for (int f = 0; f < 4; ++f)
        b[f] = *(const short8*)&Bs[(wn + f * 16 + mlane) * 64 + kk + quad * 8];
#pragma unroll
      for (int i = 0; i < 4; ++i)
#pragma unroll
        for (int j = 0; j < 4; ++j)
          acc[i][j] = __builtin_amdgcn_mfma_f32_16x16x32_bf16(a[i], b[j], acc[i][j], 0, 0, 0);
    }
  }
#pragma unroll
  for (int fn = 0; fn < 4; ++fn) {
    int col = n0 + wn + fn * 16 + mlane;
    float bv = bias[col];
#pragma unroll
    for (int fm = 0; fm < 4; ++fm) {
      int m = m0 + wm + fm * 16 + quad * 4;
#pragma unroll
      for (int r = 0; r < 4; ++r)
        out[(size_t)(m + r) * 768 + col] = acc[fm][fn][r] + bv;
    }
  }
}

extern "C" void kernel_launch(void* const* d_in, const int* in_sizes, int n_in,
                              void* d_out, int out_size, void* d_ws, size_t ws_size,
                              hipStream_t stream) {
  const float* x = (const float*)d_in[0];
  const float* Wqkv = (const float*)d_in[1];
  const float* Wproj = (const float*)d_in[2];
  const float* bias = (const float*)d_in[3];
  const float* temp = (const float*)d_in[4];
  float* out = (float*)d_out;

  char* ws = (char*)d_ws;
  size_t off = 0;
  auto alloc = [&](size_t bytes) -> void* {
    void* p = ws + off;
    off += (bytes + 255) & ~(size_t)255;
    return p;
  };
  unsigned short* xb = (unsigned short*)alloc(32768ull * 768 * 2);  // reused as y after gemm_qkv
  unsigned short* Wtq = (unsigned short*)alloc(2304ull * 768 * 2);
  unsigned short* Wtp = (unsigned short*)alloc(768ull * 768 * 2);
  unsigned short* Q = (unsigned short*)alloc(64ull * 4096 * 96 * 2);
  unsigned short* Kd = (unsigned short*)alloc(64ull * 4096 * 96 * 2);
  unsigned short* V = (unsigned short*)alloc(64ull * 4096 * 96 * 2);
  float* sq = (float*)alloc(64 * 96 * 4);
  float* sk = (float*)alloc(64 * 96 * 4);
  unsigned short* P = (unsigned short*)alloc(64ull * 9216 * 2);
  (void)off; (void)ws_size; (void)in_sizes; (void)n_in; (void)out_size;

  // Spart (64*16*9216 fp32 = 37.75 MB) staged in d_out (100 MB), which is
  // only written by gemm_proj at the very end — stream-ordered, no race.
  float* Spart = out;

  // one-time: allow 128 KiB dynamic LDS for the 256x256 pipelined GEMM
  static bool attr_set = false;
  if (!attr_set) {
    hipFuncSetAttribute((const void*)gemm_qkv, hipFuncAttributeMaxDynamicSharedMemorySize, 131072);
    attr_set = true;
  }

  cvt_x<<<4096, 256, 0, stream>>>((const float4*)x, (ushort4*)xb, 32768 * 768 / 4);
  t_wqkv<<<dim3(72, 24), 256, 0, stream>>>(Wqkv, Wtq);
  t_wproj<<<dim3(24, 24), 256, 0, stream>>>(Wproj, Wtp);
  hipMemsetAsync(sq, 0, 64 * 96 * 4, stream);
  hipMemsetAsync(sk, 0, 64 * 96 * 4, stream);
  gemm_qkv<<<dim3(128, 9), 512, 131072, stream>>>(xb, Wtq, Q, Kd, V);
  attn_partial<<<dim3(16, 64), 256, 0, stream>>>(Q, Kd, Spart, sq, sk);
  attn_finalize<<<64, 256, 0, stream>>>(Spart, sq, sk, temp, P);
  gemm_pv<<<dim3(32, 64), 256, 0, stream>>>(V, P, xb /*y*/);
  gemm_proj<<<dim3(256, 6), 256, 0, stream>>>(xb /*y*/, Wtp, bias, out);
}

// Round 7
// 473.050 us; speedup vs baseline: 1.1674x; 1.0359x over previous
//
#include <hip/hip_runtime.h>

typedef __attribute__((ext_vector_type(8))) short short8;
typedef __attribute__((ext_vector_type(4))) float f32x4;

__device__ inline unsigned short f2b(float f) {
  unsigned int u = __builtin_bit_cast(unsigned int, f);
  u = (u + 0x7FFFu + ((u >> 16) & 1u)) >> 16;
  return (unsigned short)u;
}
__device__ inline float b2f(unsigned short s) {
  unsigned int u = ((unsigned int)s) << 16;
  return __builtin_bit_cast(float, u);
}

__device__ inline void async16(const void* g, void* l) {
  __builtin_amdgcn_global_load_lds((__attribute__((address_space(1))) void*)(g),
                                   (__attribute__((address_space(3))) void*)(l), 16, 0, 0);
}

// ---------------- x fp32 -> bf16 ----------------
__global__ void cvt_x(const float4* __restrict__ x, ushort4* __restrict__ xb, int n4) {
  int i = blockIdx.x * blockDim.x + threadIdx.x;
  int stride = gridDim.x * blockDim.x;
  for (; i < n4; i += stride) {
    float4 v = x[i];
    ushort4 o;
    o.x = f2b(v.x); o.y = f2b(v.y); o.z = f2b(v.z); o.w = f2b(v.w);
    xb[i] = o;
  }
}

// ---------------- W_qkv [768][2304] -> Wt [2304(perm s,h,d)][768] bf16 ----------------
__global__ __launch_bounds__(256) void t_wqkv(const float* __restrict__ W, unsigned short* __restrict__ Wt) {
  __shared__ float tile[32][33];
  int j0 = blockIdx.x * 32, c0 = blockIdx.y * 32;
  int tx = threadIdx.x & 31, ty = threadIdx.x >> 5;
#pragma unroll
  for (int r = 0; r < 32; r += 8)
    tile[ty + r][tx] = W[(size_t)(c0 + ty + r) * 2304 + j0 + tx];
  __syncthreads();
#pragma unroll
  for (int r = 0; r < 32; r += 8) {
    int j = j0 + ty + r;
    int h = j / 288, rem = j - h * 288;
    int d = rem / 3, s = rem - d * 3;
    int jj = s * 768 + h * 96 + d;
    Wt[(size_t)jj * 768 + c0 + tx] = f2b(tile[tx][ty + r]);
  }
}

// ---------------- W_proj [768][768] -> Wt [768][768] bf16 (transpose) ----------------
__global__ __launch_bounds__(256) void t_wproj(const float* __restrict__ W, unsigned short* __restrict__ Wt) {
  __shared__ float tile[32][33];
  int j0 = blockIdx.x * 32, c0 = blockIdx.y * 32;
  int tx = threadIdx.x & 31, ty = threadIdx.x >> 5;
#pragma unroll
  for (int r = 0; r < 32; r += 8)
    tile[ty + r][tx] = W[(size_t)(c0 + ty + r) * 768 + j0 + tx];
  __syncthreads();
#pragma unroll
  for (int r = 0; r < 32; r += 8)
    Wt[(size_t)(j0 + ty + r) * 768 + c0 + tx] = f2b(tile[tx][ty + r]);
}

// ---------------- GEMM1: qkv = xb @ Wqkv, 256x256 tile, 4-phase interleaved ----------------
// (unchanged from round 6: proven 149 us, 0 bank conflicts)
__global__ __launch_bounds__(512, 2) void gemm_qkv(
    const unsigned short* __restrict__ A, const unsigned short* __restrict__ Bt,
    unsigned short* __restrict__ Q, unsigned short* __restrict__ Kd, unsigned short* __restrict__ V) {
  extern __shared__ __align__(16) unsigned short smem[];  // [2 bufs][4 halves][8192 elems]
  const int tid = threadIdx.x;
  const int wave = tid >> 6, lane = tid & 63;
  const int mlane = lane & 15, quad = lane >> 4;
  const int m0 = blockIdx.x * 256, n0 = blockIdx.y * 256;
  const int ah = wave >> 2;
  const int wm = ah * 128;
  const int wn = (wave & 3) * 64;
  const int bh = wn >> 7;
  const int bl = wn & 64;

  f32x4 acc[8][4] = {};

  auto stage = [&](int kt, int c) {
    const int k0 = kt * 64;
#pragma unroll
    for (int h = 0; h < 4; ++h) {
      const unsigned short* src = (h < 2) ? A : Bt;
      const int rbase = ((h < 2) ? m0 : n0) + (h & 1) * 128;
      unsigned short* ldsbase = smem + c * 32768 + h * 8192;
#pragma unroll
      for (int i = 0; i < 2; ++i) {
        int ebase = i * 512 + (wave << 6);
        int e = ebase + lane;
        int row = e >> 3;
        int slot = (e & 7) ^ (row & 7);
        async16(src + (size_t)(rbase + row) * 768 + k0 + slot * 8, ldsbase + ebase * 8);
      }
    }
  };

  auto rdA = [&](const unsigned short* base, int mh, int kk, int f) -> short8 {
    int r = mh * 64 + f * 16 + mlane;
    return *(const short8*)&base[r * 64 + ((kk * 32 + quad * 8) ^ ((r & 7) << 3))];
  };
  auto rdB = [&](const unsigned short* base, int kk, int j) -> short8 {
    int r = bl + j * 16 + mlane;
    return *(const short8*)&base[r * 64 + ((kk * 32 + quad * 8) ^ ((r & 7) << 3))];
  };

  stage(0, 0);
  stage(1, 1);
  asm volatile("s_waitcnt vmcnt(8)" ::: "memory");
  __builtin_amdgcn_sched_barrier(0);
  __builtin_amdgcn_s_barrier();

#pragma unroll 1
  for (int t = 0; t < 12; ++t) {
    const int c = t & 1;
    const unsigned short* Abase = smem + c * 32768 + ah * 8192;
    const unsigned short* Bbase = smem + c * 32768 + 16384 + bh * 8192;
    short8 a0[4], a1[4], b0[4], b1[4];

#pragma unroll
    for (int j = 0; j < 4; ++j) b0[j] = rdB(Bbase, 0, j);
#pragma unroll
    for (int f = 0; f < 4; ++f) a0[f] = rdA(Abase, 0, 0, f);
    asm volatile("s_waitcnt lgkmcnt(0)" ::: "memory");
    __builtin_amdgcn_sched_barrier(0);
    __builtin_amdgcn_s_setprio(1);
#pragma unroll
    for (int f = 0; f < 4; ++f)
#pragma unroll
      for (int j = 0; j < 4; ++j)
        acc[f][j] = __builtin_amdgcn_mfma_f32_16x16x32_bf16(a0[f], b0[j], acc[f][j], 0, 0, 0);
    __builtin_amdgcn_s_setprio(0);
    __builtin_amdgcn_s_barrier();

#pragma unroll
    for (int f = 0; f < 4; ++f) a1[f] = rdA(Abase, 1, 0, f);
#pragma unroll
    for (int j = 0; j < 4; ++j) b1[j] = rdB(Bbase, 1, j);
    asm volatile("s_waitcnt lgkmcnt(0)" ::: "memory");
    __builtin_amdgcn_sched_barrier(0);
    __builtin_amdgcn_s_setprio(1);
#pragma unroll
    for (int f = 0; f < 4; ++f)
#pragma unroll
      for (int j = 0; j < 4; ++j)
        acc[4 + f][j] = __builtin_amdgcn_mfma_f32_16x16x32_bf16(a1[f], b0[j], acc[4 + f][j], 0, 0, 0);
    __builtin_amdgcn_s_setprio(0);
    __builtin_amdgcn_s_barrier();

#pragma unroll
    for (int f = 0; f < 4; ++f) a0[f] = rdA(Abase, 0, 1, f);
#pragma unroll
    for (int f = 0; f < 4; ++f) a1[f] = rdA(Abase, 1, 1, f);
    asm volatile("s_waitcnt lgkmcnt(0)" ::: "memory");
    __builtin_amdgcn_sched_barrier(0);
    __builtin_amdgcn_s_setprio(1);
#pragma unroll
    for (int f = 0; f < 4; ++f)
#pragma unroll
      for (int j = 0; j < 4; ++j)
        acc[f][j] = __builtin_amdgcn_mfma_f32_16x16x32_bf16(a0[f], b1[j], acc[f][j], 0, 0, 0);
    __builtin_amdgcn_s_setprio(0);
    __builtin_amdgcn_s_barrier();

    if (t < 10) stage(t + 2, c);
    __builtin_amdgcn_s_setprio(1);
#pragma unroll
    for (int f = 0; f < 4; ++f)
#pragma unroll
      for (int j = 0; j < 4; ++j)
        acc[4 + f][j] = __builtin_amdgcn_mfma_f32_16x16x32_bf16(a1[f], b1[j], acc[4 + f][j], 0, 0, 0);
    __builtin_amdgcn_s_setprio(0);
    if (t < 10) {
      asm volatile("s_waitcnt vmcnt(8)" ::: "memory");
      __builtin_amdgcn_sched_barrier(0);
      __builtin_amdgcn_s_barrier();
    } else if (t == 10) {
      asm volatile("s_waitcnt vmcnt(0)" ::: "memory");
      __builtin_amdgcn_sched_barrier(0);
      __builtin_amdgcn_s_barrier();
    }
  }

  const int bb = m0 >> 12;
  const int nbase = (m0 & 4095) + wm + quad * 4;
  unsigned short* dstp[4];
  size_t cb[4];
#pragma unroll
  for (int j = 0; j < 4; ++j) {
    int jj = n0 + wn + j * 16 + mlane;
    int s = (jj >= 1536) ? 2 : (jj >= 768) ? 1 : 0;
    int hd = jj - s * 768;
    int h = hd / 96;
    int d = hd - h * 96;
    dstp[j] = (s == 0) ? Q : (s == 1) ? Kd : V;
    cb[j] = ((size_t)(bb * 8 + h) * 4096) * 96 + d;
  }
#pragma unroll
  for (int mf = 0; mf < 8; ++mf) {
    int n = nbase + (mf >> 2) * 64 + (mf & 3) * 16;
#pragma unroll
    for (int r = 0; r < 4; ++r) {
#pragma unroll
      for (int j = 0; j < 4; ++j)
        dstp[j][cb[j] + (size_t)(n + r) * 96] = f2b(acc[mf][j][r]);
    }
  }
}

// ---------------- attn split-K partial (unchanged) ----------------
__global__ __launch_bounds__(256) void attn_partial(
    const unsigned short* __restrict__ Q, const unsigned short* __restrict__ Kd,
    float* __restrict__ Spart, float* __restrict__ sq, float* __restrict__ sk) {
  int chunk = blockIdx.x;
  int bh = blockIdx.y;
  __shared__ __align__(16) unsigned short QT[96 * 72];
  __shared__ __align__(16) unsigned short KT[96 * 72];
  int t = threadIdx.x;
  int wave = t >> 6, lane = t & 63, mlane = lane & 15, quad = lane >> 4;
  int wrow = (wave >> 1) * 48, wcol = (wave & 1) * 48;
  f32x4 acc[3][3] = {};
  const unsigned int* qp = (const unsigned int*)(Q + (size_t)bh * 4096 * 96);
  const unsigned int* kp = (const unsigned int*)(Kd + (size_t)bh * 4096 * 96);
  int c = t % 48, rg = t / 48;
  int nbeg = chunk * 256;
  float aq0 = 0.f, aq1 = 0.f, ak0 = 0.f, ak1 = 0.f;
  for (int n0 = nbeg; n0 < nbeg + 256; n0 += 64) {
    __syncthreads();
    if (rg < 5) {
      for (int n = rg; n < 64; n += 5) {
        unsigned int qv = qp[(size_t)(n0 + n) * 48 + c];
        unsigned int kv = kp[(size_t)(n0 + n) * 48 + c];
        QT[(2 * c) * 72 + n] = (unsigned short)(qv & 0xffff);
        QT[(2 * c + 1) * 72 + n] = (unsigned short)(qv >> 16);
        KT[(2 * c) * 72 + n] = (unsigned short)(kv & 0xffff);
        KT[(2 * c + 1) * 72 + n] = (unsigned short)(kv >> 16);
        float q0 = b2f((unsigned short)(qv & 0xffff)), q1 = b2f((unsigned short)(qv >> 16));
        float k0 = b2f((unsigned short)(kv & 0xffff)), k1 = b2f((unsigned short)(kv >> 16));
        aq0 += q0 * q0; aq1 += q1 * q1; ak0 += k0 * k0; ak1 += k1 * k1;
      }
    }
    __syncthreads();
#pragma unroll
    for (int kk = 0; kk < 64; kk += 32) {
      short8 a[3], bf[3];
#pragma unroll
      for (int f = 0; f < 3; ++f)
        a[f] = *(const short8*)&QT[(wrow + f * 16 + mlane) * 72 + kk + quad * 8];
#pragma unroll
      for (int f = 0; f < 3; ++f)
        bf[f] = *(const short8*)&KT[(wcol + f * 16 + mlane) * 72 + kk + quad * 8];
#pragma unroll
      for (int i = 0; i < 3; ++i)
#pragma unroll
        for (int j = 0; j < 3; ++j)
          acc[i][j] = __builtin_amdgcn_mfma_f32_16x16x32_bf16(a[i], bf[j], acc[i][j], 0, 0, 0);
    }
  }
  if (rg < 5) {
    atomicAdd(&sq[bh * 96 + 2 * c], aq0);
    atomicAdd(&sq[bh * 96 + 2 * c + 1], aq1);
    atomicAdd(&sk[bh * 96 + 2 * c], ak0);
    atomicAdd(&sk[bh * 96 + 2 * c + 1], ak1);
  }
  float* dst = Spart + ((size_t)bh * 16 + chunk) * 9216;
#pragma unroll
  for (int i = 0; i < 3; ++i)
#pragma unroll
    for (int j = 0; j < 3; ++j)
#pragma unroll
      for (int r = 0; r < 4; ++r)
        dst[(wrow + i * 16 + quad * 4 + r) * 96 + wcol + j * 16 + mlane] = acc[i][j][r];
}

// ---------------- finalize: sum partials, normalize, softmax, write P TRANSPOSED bf16 ----------------
// Pt[bh][e][d] = softmax_e(S[d][e]); transposed store makes consecutive threads (d)
// write contiguous addresses AND makes m_pre's B-operand k-contiguous.
__global__ __launch_bounds__(256) void attn_finalize(
    const float* __restrict__ Spart, const float* __restrict__ sq,
    const float* __restrict__ sk, const float* __restrict__ temp,
    unsigned short* __restrict__ Pt) {
  int bh = blockIdx.x, h = bh & 7;
  __shared__ float S[9216];
  __shared__ float rk[96], rq[96];
  int t = threadIdx.x;
  const float* base = Spart + (size_t)bh * 16 * 9216;
  if (t < 96) {
    rk[t] = rsqrtf(sk[bh * 96 + t]);
    rq[t] = rsqrtf(sq[bh * 96 + t]) * temp[h];
  }
  __syncthreads();
  for (int i = t; i < 9216; i += 256) {
    float s = 0.f;
#pragma unroll
    for (int c2 = 0; c2 < 16; ++c2) s += base[(size_t)c2 * 9216 + i];
    int d = i / 96, e = i - d * 96;
    S[i] = s * rq[d] * rk[e];
  }
  __syncthreads();
  if (t < 96) {
    int d = t;
    float mx = -1e30f;
    for (int e = 0; e < 96; ++e) mx = fmaxf(mx, S[d * 96 + e]);
    float sum = 0.f;
    for (int e = 0; e < 96; ++e) {
      float v = expf(S[d * 96 + e] - mx);
      S[d * 96 + e] = v;
      sum += v;
    }
    float inv = 1.0f / sum;
    for (int e = 0; e < 96; ++e)
      Pt[(size_t)bh * 9216 + e * 96 + d] = f2b(S[d * 96 + e] * inv);
  }
}

// ---------------- m_pre: Mt[b][c'][h*96+e] = sum_d Wtp[c'][h*96+d] * Pt[bh][e][d] ----------------
// Per (b,h): [768 x 96] = [768 x 96(d)] @ [96(d) x 96(e)]. All operands L2-resident.
__global__ __launch_bounds__(256) void m_pre(
    const unsigned short* __restrict__ Wtp, const unsigned short* __restrict__ Pt,
    unsigned short* __restrict__ Mt) {
  int bh = blockIdx.y;
  int b = bh >> 3, h = bh & 7;
  int m0 = blockIdx.x * 128;  // c' rows
  int t = threadIdx.x, wave = t >> 6, lane = t & 63, mlane = lane & 15, quad = lane >> 4;
  const unsigned short* Pb = Pt + (size_t)bh * 9216;
  f32x4 acc[2][6] = {};
#pragma unroll
  for (int kk = 0; kk < 96; kk += 32) {
    short8 a[2], bfr[6];
#pragma unroll
    for (int i = 0; i < 2; ++i)
      a[i] = *(const short8*)&Wtp[(size_t)(m0 + wave * 32 + i * 16 + mlane) * 768 + h * 96 + kk + quad * 8];
#pragma unroll
    for (int j = 0; j < 6; ++j)
      bfr[j] = *(const short8*)&Pb[(j * 16 + mlane) * 96 + kk + quad * 8];
#pragma unroll
    for (int i = 0; i < 2; ++i)
#pragma unroll
      for (int j = 0; j < 6; ++j)
        acc[i][j] = __builtin_amdgcn_mfma_f32_16x16x32_bf16(a[i], bfr[j], acc[i][j], 0, 0, 0);
  }
#pragma unroll
  for (int i = 0; i < 2; ++i) {
    int cp = m0 + wave * 32 + i * 16 + quad * 4;
#pragma unroll
    for (int j = 0; j < 6; ++j) {
      int e = j * 16 + mlane;
#pragma unroll
      for (int r = 0; r < 4; ++r)
        Mt[((size_t)b * 768 + cp + r) * 768 + h * 96 + e] = f2b(acc[i][j][r]);
    }
  }
}

// ---------------- gemm_out: out = V_cat @ Mt + bias (fused PV+proj), 256x256 4-phase ----------------
// A[m=b*4096+n][k=h*96+e] gathered from V[(b*8+h)][n][e]; Bt = Mt[b][col][k].
__global__ __launch_bounds__(512, 2) void gemm_out(
    const unsigned short* __restrict__ V, const unsigned short* __restrict__ Mt,
    const float* __restrict__ bias, float* __restrict__ out) {
  extern __shared__ __align__(16) unsigned short smem[];
  const int tid = threadIdx.x;
  const int wave = tid >> 6, lane = tid & 63;
  const int mlane = lane & 15, quad = lane >> 4;
  const int m0 = blockIdx.x * 256, n0 = blockIdx.y * 256;
  const int bb = m0 >> 12;          // batch (block-uniform)
  const int nloc0 = m0 & 4095;      // n within batch
  const int ah = wave >> 2;
  const int wm = ah * 128;
  const int wn = (wave & 3) * 64;
  const int bhf = wn >> 7;
  const int bl = wn & 64;

  f32x4 acc[8][4] = {};

  auto stage = [&](int kt, int c) {
#pragma unroll
    for (int h = 0; h < 4; ++h) {
      unsigned short* ldsbase = smem + c * 32768 + h * 8192;
#pragma unroll
      for (int i = 0; i < 2; ++i) {
        int ebase = i * 512 + (wave << 6);
        int e = ebase + lane;
        int row = e >> 3;
        int slot = (e & 7) ^ (row & 7);
        if (h < 2) {
          // A: gather from V. k-chunk kc = kt*8+slot -> head hh, elem base e0
          int kc = kt * 8 + slot;
          int hh = kc / 12;
          int e0 = (kc - hh * 12) * 8;
          int n = nloc0 + (h & 1) * 128 + row;
          async16(V + ((size_t)(bb * 8 + hh) * 4096 + n) * 96 + e0, ldsbase + ebase * 8);
        } else {
          int col = n0 + (h & 1) * 128 + row;
          async16(Mt + ((size_t)bb * 768 + col) * 768 + kt * 64 + slot * 8, ldsbase + ebase * 8);
        }
      }
    }
  };

  auto rdA = [&](const unsigned short* base, int mh, int kk, int f) -> short8 {
    int r = mh * 64 + f * 16 + mlane;
    return *(const short8*)&base[r * 64 + ((kk * 32 + quad * 8) ^ ((r & 7) << 3))];
  };
  auto rdB = [&](const unsigned short* base, int kk, int j) -> short8 {
    int r = bl + j * 16 + mlane;
    return *(const short8*)&base[r * 64 + ((kk * 32 + quad * 8) ^ ((r & 7) << 3))];
  };

  stage(0, 0);
  stage(1, 1);
  asm volatile("s_waitcnt vmcnt(8)" ::: "memory");
  __builtin_amdgcn_sched_barrier(0);
  __builtin_amdgcn_s_barrier();

#pragma unroll 1
  for (int t = 0; t < 12; ++t) {
    const int c = t & 1;
    const unsigned short* Abase = smem + c * 32768 + ah * 8192;
    const unsigned short* Bbase = smem + c * 32768 + 16384 + bhf * 8192;
    short8 a0[4], a1[4], b0[4], b1[4];

#pragma unroll
    for (int j = 0; j < 4; ++j) b0[j] = rdB(Bbase, 0, j);
#pragma unroll
    for (int f = 0; f < 4; ++f) a0[f] = rdA(Abase, 0, 0, f);
    asm volatile("s_waitcnt lgkmcnt(0)" ::: "memory");
    __builtin_amdgcn_sched_barrier(0);
    __builtin_amdgcn_s_setprio(1);
#pragma unroll
    for (int f = 0; f < 4; ++f)
#pragma unroll
      for (int j = 0; j < 4; ++j)
        acc[f][j] = __builtin_amdgcn_mfma_f32_16x16x32_bf16(a0[f], b0[j], acc[f][j], 0, 0, 0);
    __builtin_amdgcn_s_setprio(0);
    __builtin_amdgcn_s_barrier();

#pragma unroll
    for (int f = 0; f < 4; ++f) a1[f] = rdA(Abase, 1, 0, f);
#pragma unroll
    for (int j = 0; j < 4; ++j) b1[j] = rdB(Bbase, 1, j);
    asm volatile("s_waitcnt lgkmcnt(0)" ::: "memory");
    __builtin_amdgcn_sched_barrier(0);
    __builtin_amdgcn_s_setprio(1);
#pragma unroll
    for (int f = 0; f < 4; ++f)
#pragma unroll
      for (int j = 0; j < 4; ++j)
        acc[4 + f][j] = __builtin_amdgcn_mfma_f32_16x16x32_bf16(a1[f], b0[j], acc[4 + f][j], 0, 0, 0);
    __builtin_amdgcn_s_setprio(0);
    __builtin_amdgcn_s_barrier();

#pragma unroll
    for (int f = 0; f < 4; ++f) a0[f] = rdA(Abase, 0, 1, f);
#pragma unroll
    for (int f = 0; f < 4; ++f) a1[f] = rdA(Abase, 1, 1, f);
    asm volatile("s_waitcnt lgkmcnt(0)" ::: "memory");
    __builtin_amdgcn_sched_barrier(0);
    __builtin_amdgcn_s_setprio(1);
#pragma unroll
    for (int f = 0; f < 4; ++f)
#pragma unroll
      for (int j = 0; j < 4; ++j)
        acc[f][j] = __builtin_amdgcn_mfma_f32_16x16x32_bf16(a0[f], b1[j], acc[f][j], 0, 0, 0);
    __builtin_amdgcn_s_setprio(0);
    __builtin_amdgcn_s_barrier();

    if (t < 10) stage(t + 2, c);
    __builtin_amdgcn_s_setprio(1);
#pragma unroll
    for (int f = 0; f < 4; ++f)
#pragma unroll
      for (int j = 0; j < 4; ++j)
        acc[4 + f][j] = __builtin_amdgcn_mfma_f32_16x16x32_bf16(a1[f], b1[j], acc[4 + f][j], 0, 0, 0);
    __builtin_amdgcn_s_setprio(0);
    if (t < 10) {
      asm volatile("s_waitcnt vmcnt(8)" ::: "memory");
      __builtin_amdgcn_sched_barrier(0);
      __builtin_amdgcn_s_barrier();
    } else if (t == 10) {
      asm volatile("s_waitcnt vmcnt(0)" ::: "memory");
      __builtin_amdgcn_sched_barrier(0);
      __builtin_amdgcn_s_barrier();
    }
  }

  // epilogue: fp32 out + bias, row-major contiguous
#pragma unroll
  for (int j = 0; j < 4; ++j) {
    int col = n0 + wn + j * 16 + mlane;
    float bv = bias[col];
#pragma unroll
    for (int mf = 0; mf < 8; ++mf) {
      int m = m0 + wm + (mf >> 2) * 64 + (mf & 3) * 16 + quad * 4;
#pragma unroll
      for (int r = 0; r < 4; ++r)
        out[(size_t)(m + r) * 768 + col] = acc[mf][j][r] + bv;
    }
  }
}

extern "C" void kernel_launch(void* const* d_in, const int* in_sizes, int n_in,
                              void* d_out, int out_size, void* d_ws, size_t ws_size,
                              hipStream_t stream) {
  const float* x = (const float*)d_in[0];
  const float* Wqkv = (const float*)d_in[1];
  const float* Wproj = (const float*)d_in[2];
  const float* bias = (const float*)d_in[3];
  const float* temp = (const float*)d_in[4];
  float* out = (float*)d_out;

  char* ws = (char*)d_ws;
  size_t off = 0;
  auto alloc = [&](size_t bytes) -> void* {
    void* p = ws + off;
    off += (bytes + 255) & ~(size_t)255;
    return p;
  };
  unsigned short* xb = (unsigned short*)alloc(32768ull * 768 * 2);
  unsigned short* Wtq = (unsigned short*)alloc(2304ull * 768 * 2);
  unsigned short* Wtp = (unsigned short*)alloc(768ull * 768 * 2);
  unsigned short* Q = (unsigned short*)alloc(64ull * 4096 * 96 * 2);
  unsigned short* Kd = (unsigned short*)alloc(64ull * 4096 * 96 * 2);
  unsigned short* V = (unsigned short*)alloc(64ull * 4096 * 96 * 2);
  float* sq = (float*)alloc(64 * 96 * 4);
  float* sk = (float*)alloc(64 * 96 * 4);
  unsigned short* Pt = (unsigned short*)alloc(64ull * 9216 * 2);
  (void)off; (void)ws_size; (void)in_sizes; (void)n_in; (void)out_size;

  // Mt [8][768][768] bf16 (9.4 MB) aliases xb: xb is dead after gemm_qkv,
  // m_pre writes Mt after attn_finalize — stream-ordered, no race.
  unsigned short* Mt = xb;

  // Spart (37.75 MB) staged in d_out (100 MB): only gemm_out writes out, at the end.
  float* Spart = out;

  static bool attr_set = false;
  if (!attr_set) {
    hipFuncSetAttribute((const void*)gemm_qkv, hipFuncAttributeMaxDynamicSharedMemorySize, 131072);
    hipFuncSetAttribute((const void*)gemm_out, hipFuncAttributeMaxDynamicSharedMemorySize, 131072);
    attr_set = true;
  }

  cvt_x<<<4096, 256, 0, stream>>>((const float4*)x, (ushort4*)xb, 32768 * 768 / 4);
  t_wqkv<<<dim3(72, 24), 256, 0, stream>>>(Wqkv, Wtq);
  t_wproj<<<dim3(24, 24), 256, 0, stream>>>(Wproj, Wtp);
  hipMemsetAsync(sq, 0, 64 * 96 * 4, stream);
  hipMemsetAsync(sk, 0, 64 * 96 * 4, stream);
  gemm_qkv<<<dim3(128, 9), 512, 131072, stream>>>(xb, Wtq, Q, Kd, V);
  attn_partial<<<dim3(16, 64), 256, 0, stream>>>(Q, Kd, Spart, sq, sk);
  attn_finalize<<<64, 256, 0, stream>>>(Spart, sq, sk, temp, Pt);
  m_pre<<<dim3(6, 64), 256, 0, stream>>>(Wtp, Pt, Mt);
  gemm_out<<<dim3(128, 3), 512, 131072, stream>>>(V, Mt, bias, out);
}

// Round 8
// 466.878 us; speedup vs baseline: 1.1829x; 1.0132x over previous
//
#include <hip/hip_runtime.h>

typedef __attribute__((ext_vector_type(8))) short short8;
typedef __attribute__((ext_vector_type(4))) float f32x4;

__device__ inline unsigned short f2b(float f) {
  unsigned int u = __builtin_bit_cast(unsigned int, f);
  u = (u + 0x7FFFu + ((u >> 16) & 1u)) >> 16;
  return (unsigned short)u;
}
__device__ inline float b2f(unsigned short s) {
  unsigned int u = ((unsigned int)s) << 16;
  return __builtin_bit_cast(float, u);
}

__device__ inline void async16(const void* g, void* l) {
  __builtin_amdgcn_global_load_lds((__attribute__((address_space(1))) void*)(g),
                                   (__attribute__((address_space(3))) void*)(l), 16, 0, 0);
}

// ---------------- x fp32 -> bf16 ----------------
__global__ void cvt_x(const float4* __restrict__ x, ushort4* __restrict__ xb, int n4) {
  int i = blockIdx.x * blockDim.x + threadIdx.x;
  int stride = gridDim.x * blockDim.x;
  for (; i < n4; i += stride) {
    float4 v = x[i];
    ushort4 o;
    o.x = f2b(v.x); o.y = f2b(v.y); o.z = f2b(v.z); o.w = f2b(v.w);
    xb[i] = o;
  }
}

// ---------------- W_qkv [768][2304] -> Wt [2304(perm s,h,d)][768] bf16 ----------------
__global__ __launch_bounds__(256) void t_wqkv(const float* __restrict__ W, unsigned short* __restrict__ Wt) {
  __shared__ float tile[32][33];
  int j0 = blockIdx.x * 32, c0 = blockIdx.y * 32;
  int tx = threadIdx.x & 31, ty = threadIdx.x >> 5;
#pragma unroll
  for (int r = 0; r < 32; r += 8)
    tile[ty + r][tx] = W[(size_t)(c0 + ty + r) * 2304 + j0 + tx];
  __syncthreads();
#pragma unroll
  for (int r = 0; r < 32; r += 8) {
    int j = j0 + ty + r;
    int h = j / 288, rem = j - h * 288;
    int d = rem / 3, s = rem - d * 3;
    int jj = s * 768 + h * 96 + d;
    Wt[(size_t)jj * 768 + c0 + tx] = f2b(tile[tx][ty + r]);
  }
}

// ---------------- W_proj [768][768] -> Wt [768][768] bf16 (transpose) ----------------
__global__ __launch_bounds__(256) void t_wproj(const float* __restrict__ W, unsigned short* __restrict__ Wt) {
  __shared__ float tile[32][33];
  int j0 = blockIdx.x * 32, c0 = blockIdx.y * 32;
  int tx = threadIdx.x & 31, ty = threadIdx.x >> 5;
#pragma unroll
  for (int r = 0; r < 32; r += 8)
    tile[ty + r][tx] = W[(size_t)(c0 + ty + r) * 768 + j0 + tx];
  __syncthreads();
#pragma unroll
  for (int r = 0; r < 32; r += 8)
    Wt[(size_t)(j0 + ty + r) * 768 + c0 + tx] = f2b(tile[tx][ty + r]);
}

// ---------------- GEMM1: qkv = xb @ Wqkv, 256x256 tile, 4-phase interleaved ----------------
// K-loop unchanged from round 6 (149 us, 0 conflicts). Epilogue: Q/K stored TRANSPOSED
// Qt/Kt[bh][d][n] (ushort4 stores, fused sumsq; s is block-uniform); V n-major as before.
__global__ __launch_bounds__(512, 2) void gemm_qkv(
    const unsigned short* __restrict__ A, const unsigned short* __restrict__ Bt,
    unsigned short* __restrict__ Qt, unsigned short* __restrict__ Kt, unsigned short* __restrict__ V,
    float* __restrict__ sq, float* __restrict__ sk) {
  extern __shared__ __align__(16) unsigned short smem[];
  const int tid = threadIdx.x;
  const int wave = tid >> 6, lane = tid & 63;
  const int mlane = lane & 15, quad = lane >> 4;
  const int m0 = blockIdx.x * 256, n0 = blockIdx.y * 256;
  const int ah = wave >> 2;
  const int wm = ah * 128;
  const int wn = (wave & 3) * 64;
  const int bh = wn >> 7;
  const int bl = wn & 64;

  f32x4 acc[8][4] = {};

  auto stage = [&](int kt, int c) {
    const int k0 = kt * 64;
#pragma unroll
    for (int h = 0; h < 4; ++h) {
      const unsigned short* src = (h < 2) ? A : Bt;
      const int rbase = ((h < 2) ? m0 : n0) + (h & 1) * 128;
      unsigned short* ldsbase = smem + c * 32768 + h * 8192;
#pragma unroll
      for (int i = 0; i < 2; ++i) {
        int ebase = i * 512 + (wave << 6);
        int e = ebase + lane;
        int row = e >> 3;
        int slot = (e & 7) ^ (row & 7);
        async16(src + (size_t)(rbase + row) * 768 + k0 + slot * 8, ldsbase + ebase * 8);
      }
    }
  };

  auto rdA = [&](const unsigned short* base, int mh, int kk, int f) -> short8 {
    int r = mh * 64 + f * 16 + mlane;
    return *(const short8*)&base[r * 64 + ((kk * 32 + quad * 8) ^ ((r & 7) << 3))];
  };
  auto rdB = [&](const unsigned short* base, int kk, int j) -> short8 {
    int r = bl + j * 16 + mlane;
    return *(const short8*)&base[r * 64 + ((kk * 32 + quad * 8) ^ ((r & 7) << 3))];
  };

  stage(0, 0);
  stage(1, 1);
  asm volatile("s_waitcnt vmcnt(8)" ::: "memory");
  __builtin_amdgcn_sched_barrier(0);
  __builtin_amdgcn_s_barrier();

#pragma unroll 1
  for (int t = 0; t < 12; ++t) {
    const int c = t & 1;
    const unsigned short* Abase = smem + c * 32768 + ah * 8192;
    const unsigned short* Bbase = smem + c * 32768 + 16384 + bh * 8192;
    short8 a0[4], a1[4], b0[4], b1[4];

#pragma unroll
    for (int j = 0; j < 4; ++j) b0[j] = rdB(Bbase, 0, j);
#pragma unroll
    for (int f = 0; f < 4; ++f) a0[f] = rdA(Abase, 0, 0, f);
    asm volatile("s_waitcnt lgkmcnt(0)" ::: "memory");
    __builtin_amdgcn_sched_barrier(0);
    __builtin_amdgcn_s_setprio(1);
#pragma unroll
    for (int f = 0; f < 4; ++f)
#pragma unroll
      for (int j = 0; j < 4; ++j)
        acc[f][j] = __builtin_amdgcn_mfma_f32_16x16x32_bf16(a0[f], b0[j], acc[f][j], 0, 0, 0);
    __builtin_amdgcn_s_setprio(0);
    __builtin_amdgcn_s_barrier();

#pragma unroll
    for (int f = 0; f < 4; ++f) a1[f] = rdA(Abase, 1, 0, f);
#pragma unroll
    for (int j = 0; j < 4; ++j) b1[j] = rdB(Bbase, 1, j);
    asm volatile("s_waitcnt lgkmcnt(0)" ::: "memory");
    __builtin_amdgcn_sched_barrier(0);
    __builtin_amdgcn_s_setprio(1);
#pragma unroll
    for (int f = 0; f < 4; ++f)
#pragma unroll
      for (int j = 0; j < 4; ++j)
        acc[4 + f][j] = __builtin_amdgcn_mfma_f32_16x16x32_bf16(a1[f], b0[j], acc[4 + f][j], 0, 0, 0);
    __builtin_amdgcn_s_setprio(0);
    __builtin_amdgcn_s_barrier();

#pragma unroll
    for (int f = 0; f < 4; ++f) a0[f] = rdA(Abase, 0, 1, f);
#pragma unroll
    for (int f = 0; f < 4; ++f) a1[f] = rdA(Abase, 1, 1, f);
    asm volatile("s_waitcnt lgkmcnt(0)" ::: "memory");
    __builtin_amdgcn_sched_barrier(0);
    __builtin_amdgcn_s_setprio(1);
#pragma unroll
    for (int f = 0; f < 4; ++f)
#pragma unroll
      for (int j = 0; j < 4; ++j)
        acc[f][j] = __builtin_amdgcn_mfma_f32_16x16x32_bf16(a0[f], b1[j], acc[f][j], 0, 0, 0);
    __builtin_amdgcn_s_setprio(0);
    __builtin_amdgcn_s_barrier();

    if (t < 10) stage(t + 2, c);
    __builtin_amdgcn_s_setprio(1);
#pragma unroll
    for (int f = 0; f < 4; ++f)
#pragma unroll
      for (int j = 0; j < 4; ++j)
        acc[4 + f][j] = __builtin_amdgcn_mfma_f32_16x16x32_bf16(a1[f], b1[j], acc[4 + f][j], 0, 0, 0);
    __builtin_amdgcn_s_setprio(0);
    if (t < 10) {
      asm volatile("s_waitcnt vmcnt(8)" ::: "memory");
      __builtin_amdgcn_sched_barrier(0);
      __builtin_amdgcn_s_barrier();
    } else if (t == 10) {
      asm volatile("s_waitcnt vmcnt(0)" ::: "memory");
      __builtin_amdgcn_sched_barrier(0);
      __builtin_amdgcn_s_barrier();
    }
  }

  const int bb = m0 >> 12;
  const int s = n0 / 768;  // block-uniform (768 % 256 == 0)
  if (s < 2) {
    // ---- transposed Q/K store + fused sumsq ----
    unsigned short* dst = (s == 0) ? Qt : Kt;
    float* ss = (s == 0) ? sq : sk;
    const int n0s = n0 - s * 768;
    const int mloc = (m0 & 4095) + wm;
#pragma unroll
    for (int j = 0; j < 4; ++j) {
      int hd = n0s + wn + j * 16 + mlane;  // h*96+d
      int h = hd / 96, d = hd - h * 96;
      size_t rowbase = ((size_t)(bb * 8 + h) * 96 + d) * 4096 + mloc;
      float ssq = 0.f;
#pragma unroll
      for (int mf = 0; mf < 8; ++mf) {
        int nl = (mf >> 2) * 64 + (mf & 3) * 16 + quad * 4;
        ushort4 o;
        o.x = f2b(acc[mf][j][0]); o.y = f2b(acc[mf][j][1]);
        o.z = f2b(acc[mf][j][2]); o.w = f2b(acc[mf][j][3]);
        *(ushort4*)(dst + rowbase + nl) = o;
#pragma unroll
        for (int r = 0; r < 4; ++r) ssq += acc[mf][j][r] * acc[mf][j][r];
      }
      ssq += __shfl_xor(ssq, 16);
      ssq += __shfl_xor(ssq, 32);
      if (quad == 0) atomicAdd(&ss[(bb * 8 + h) * 96 + d], ssq);
    }
  } else {
    // ---- V scatter (n-major), j-innermost for contiguous bursts ----
    const int nbase = (m0 & 4095) + wm + quad * 4;
    size_t cb[4];
#pragma unroll
    for (int j = 0; j < 4; ++j) {
      int hd = n0 + wn + j * 16 + mlane - 1536;
      int h = hd / 96;
      int d = hd - h * 96;
      cb[j] = ((size_t)(bb * 8 + h) * 4096) * 96 + d;
    }
#pragma unroll
    for (int mf = 0; mf < 8; ++mf) {
      int n = nbase + (mf >> 2) * 64 + (mf & 3) * 16;
#pragma unroll
      for (int r = 0; r < 4; ++r) {
#pragma unroll
        for (int j = 0; j < 4; ++j)
          V[cb[j] + (size_t)(n + r) * 96] = f2b(acc[mf][j][r]);
      }
    }
  }
}

// ---------------- attn split-K partial: Spart[bh][chunk][96][96] fp32 ----------------
// LDS-free: MFMA fragments read DIRECTLY from global Qt/Kt[bh][d][n] (k=n contiguous,
// 64B segments per row, L2-resident). No barriers; next-step fragments prefetched.
__global__ __launch_bounds__(256) void attn_partial(
    const unsigned short* __restrict__ Qt, const unsigned short* __restrict__ Kt,
    float* __restrict__ Spart) {
  int chunk = blockIdx.x;  // 16 chunks of 256 n
  int bh = blockIdx.y;
  int t = threadIdx.x;
  int wave = t >> 6, lane = t & 63, mlane = lane & 15, quad = lane >> 4;
  int wrow = (wave >> 1) * 48, wcol = (wave & 1) * 48;
  const unsigned short* qp = Qt + (size_t)bh * 96 * 4096;
  const unsigned short* kp = Kt + (size_t)bh * 96 * 4096;
  f32x4 acc[3][3] = {};
  int nbeg = chunk * 256;

  short8 a[3], b[3], an[3], bn[3];
#pragma unroll
  for (int f = 0; f < 3; ++f) {
    a[f] = *(const short8*)&qp[(size_t)(wrow + f * 16 + mlane) * 4096 + nbeg + quad * 8];
    b[f] = *(const short8*)&kp[(size_t)(wcol + f * 16 + mlane) * 4096 + nbeg + quad * 8];
  }
#pragma unroll 1
  for (int n0 = nbeg; n0 < nbeg + 256; n0 += 32) {
    if (n0 + 32 < nbeg + 256) {
#pragma unroll
      for (int f = 0; f < 3; ++f) {
        an[f] = *(const short8*)&qp[(size_t)(wrow + f * 16 + mlane) * 4096 + n0 + 32 + quad * 8];
        bn[f] = *(const short8*)&kp[(size_t)(wcol + f * 16 + mlane) * 4096 + n0 + 32 + quad * 8];
      }
    }
#pragma unroll
    for (int i = 0; i < 3; ++i)
#pragma unroll
      for (int j = 0; j < 3; ++j)
        acc[i][j] = __builtin_amdgcn_mfma_f32_16x16x32_bf16(a[i], b[j], acc[i][j], 0, 0, 0);
#pragma unroll
    for (int f = 0; f < 3; ++f) { a[f] = an[f]; b[f] = bn[f]; }
  }
  float* dst = Spart + ((size_t)bh * 16 + chunk) * 9216;
#pragma unroll
  for (int i = 0; i < 3; ++i)
#pragma unroll
    for (int j = 0; j < 3; ++j)
#pragma unroll
      for (int r = 0; r < 4; ++r)
        dst[(wrow + i * 16 + quad * 4 + r) * 96 + wcol + j * 16 + mlane] = acc[i][j][r];
}

// ---------------- finalize: sum partials, normalize, softmax, write P TRANSPOSED bf16 ----------------
__global__ __launch_bounds__(256) void attn_finalize(
    const float* __restrict__ Spart, const float* __restrict__ sq,
    const float* __restrict__ sk, const float* __restrict__ temp,
    unsigned short* __restrict__ Pt) {
  int bh = blockIdx.x, h = bh & 7;
  __shared__ float S[9216];
  __shared__ float rk[96], rq[96];
  int t = threadIdx.x;
  const float* base = Spart + (size_t)bh * 16 * 9216;
  if (t < 96) {
    rk[t] = rsqrtf(sk[bh * 96 + t]);
    rq[t] = rsqrtf(sq[bh * 96 + t]) * temp[h];
  }
  __syncthreads();
  for (int i = t; i < 9216; i += 256) {
    float s = 0.f;
#pragma unroll
    for (int c2 = 0; c2 < 16; ++c2) s += base[(size_t)c2 * 9216 + i];
    int d = i / 96, e = i - d * 96;
    S[i] = s * rq[d] * rk[e];
  }
  __syncthreads();
  if (t < 96) {
    int d = t;
    float mx = -1e30f;
    for (int e = 0; e < 96; ++e) mx = fmaxf(mx, S[d * 96 + e]);
    float sum = 0.f;
    for (int e = 0; e < 96; ++e) {
      float v = expf(S[d * 96 + e] - mx);
      S[d * 96 + e] = v;
      sum += v;
    }
    float inv = 1.0f / sum;
    for (int e = 0; e < 96; ++e)
      Pt[(size_t)bh * 9216 + e * 96 + d] = f2b(S[d * 96 + e] * inv);
  }
}

// ---------------- m_pre: Mt[b][c'][h*96+e] = sum_d Wtp[c'][h*96+d] * Pt[bh][e][d] ----------------
__global__ __launch_bounds__(256) void m_pre(
    const unsigned short* __restrict__ Wtp, const unsigned short* __restrict__ Pt,
    unsigned short* __restrict__ Mt) {
  int bh = blockIdx.y;
  int b = bh >> 3, h = bh & 7;
  int m0 = blockIdx.x * 128;
  int t = threadIdx.x, wave = t >> 6, lane = t & 63, mlane = lane & 15, quad = lane >> 4;
  const unsigned short* Pb = Pt + (size_t)bh * 9216;
  f32x4 acc[2][6] = {};
#pragma unroll
  for (int kk = 0; kk < 96; kk += 32) {
    short8 a[2], bfr[6];
#pragma unroll
    for (int i = 0; i < 2; ++i)
      a[i] = *(const short8*)&Wtp[(size_t)(m0 + wave * 32 + i * 16 + mlane) * 768 + h * 96 + kk + quad * 8];
#pragma unroll
    for (int j = 0; j < 6; ++j)
      bfr[j] = *(const short8*)&Pb[(j * 16 + mlane) * 96 + kk + quad * 8];
#pragma unroll
    for (int i = 0; i < 2; ++i)
#pragma unroll
      for (int j = 0; j < 6; ++j)
        acc[i][j] = __builtin_amdgcn_mfma_f32_16x16x32_bf16(a[i], bfr[j], acc[i][j], 0, 0, 0);
  }
#pragma unroll
  for (int i = 0; i < 2; ++i) {
    int cp = m0 + wave * 32 + i * 16 + quad * 4;
#pragma unroll
    for (int j = 0; j < 6; ++j) {
      int e = j * 16 + mlane;
#pragma unroll
      for (int r = 0; r < 4; ++r)
        Mt[((size_t)b * 768 + cp + r) * 768 + h * 96 + e] = f2b(acc[i][j][r]);
    }
  }
}

// ---------------- gemm_out: out = V_cat @ Mt + bias (fused PV+proj), 256x256 4-phase ----------------
__global__ __launch_bounds__(512, 2) void gemm_out(
    const unsigned short* __restrict__ V, const unsigned short* __restrict__ Mt,
    const float* __restrict__ bias, float* __restrict__ out) {
  extern __shared__ __align__(16) unsigned short smem[];
  const int tid = threadIdx.x;
  const int wave = tid >> 6, lane = tid & 63;
  const int mlane = lane & 15, quad = lane >> 4;
  const int m0 = blockIdx.x * 256, n0 = blockIdx.y * 256;
  const int bb = m0 >> 12;
  const int nloc0 = m0 & 4095;
  const int ah = wave >> 2;
  const int wm = ah * 128;
  const int wn = (wave & 3) * 64;
  const int bhf = wn >> 7;
  const int bl = wn & 64;

  f32x4 acc[8][4] = {};

  auto stage = [&](int kt, int c) {
#pragma unroll
    for (int h = 0; h < 4; ++h) {
      unsigned short* ldsbase = smem + c * 32768 + h * 8192;
#pragma unroll
      for (int i = 0; i < 2; ++i) {
        int ebase = i * 512 + (wave << 6);
        int e = ebase + lane;
        int row = e >> 3;
        int slot = (e & 7) ^ (row & 7);
        if (h < 2) {
          int kc = kt * 8 + slot;
          int hh = kc / 12;
          int e0 = (kc - hh * 12) * 8;
          int n = nloc0 + (h & 1) * 128 + row;
          async16(V + ((size_t)(bb * 8 + hh) * 4096 + n) * 96 + e0, ldsbase + ebase * 8);
        } else {
          int col = n0 + (h & 1) * 128 + row;
          async16(Mt + ((size_t)bb * 768 + col) * 768 + kt * 64 + slot * 8, ldsbase + ebase * 8);
        }
      }
    }
  };

  auto rdA = [&](const unsigned short* base, int mh, int kk, int f) -> short8 {
    int r = mh * 64 + f * 16 + mlane;
    return *(const short8*)&base[r * 64 + ((kk * 32 + quad * 8) ^ ((r & 7) << 3))];
  };
  auto rdB = [&](const unsigned short* base, int kk, int j) -> short8 {
    int r = bl + j * 16 + mlane;
    return *(const short8*)&base[r * 64 + ((kk * 32 + quad * 8) ^ ((r & 7) << 3))];
  };

  stage(0, 0);
  stage(1, 1);
  asm volatile("s_waitcnt vmcnt(8)" ::: "memory");
  __builtin_amdgcn_sched_barrier(0);
  __builtin_amdgcn_s_barrier();

#pragma unroll 1
  for (int t = 0; t < 12; ++t) {
    const int c = t & 1;
    const unsigned short* Abase = smem + c * 32768 + ah * 8192;
    const unsigned short* Bbase = smem + c * 32768 + 16384 + bhf * 8192;
    short8 a0[4], a1[4], b0[4], b1[4];

#pragma unroll
    for (int j = 0; j < 4; ++j) b0[j] = rdB(Bbase, 0, j);
#pragma unroll
    for (int f = 0; f < 4; ++f) a0[f] = rdA(Abase, 0, 0, f);
    asm volatile("s_waitcnt lgkmcnt(0)" ::: "memory");
    __builtin_amdgcn_sched_barrier(0);
    __builtin_amdgcn_s_setprio(1);
#pragma unroll
    for (int f = 0; f < 4; ++f)
#pragma unroll
      for (int j = 0; j < 4; ++j)
        acc[f][j] = __builtin_amdgcn_mfma_f32_16x16x32_bf16(a0[f], b0[j], acc[f][j], 0, 0, 0);
    __builtin_amdgcn_s_setprio(0);
    __builtin_amdgcn_s_barrier();

#pragma unroll
    for (int f = 0; f < 4; ++f) a1[f] = rdA(Abase, 1, 0, f);
#pragma unroll
    for (int j = 0; j < 4; ++j) b1[j] = rdB(Bbase, 1, j);
    asm volatile("s_waitcnt lgkmcnt(0)" ::: "memory");
    __builtin_amdgcn_sched_barrier(0);
    __builtin_amdgcn_s_setprio(1);
#pragma unroll
    for (int f = 0; f < 4; ++f)
#pragma unroll
      for (int j = 0; j < 4; ++j)
        acc[4 + f][j] = __builtin_amdgcn_mfma_f32_16x16x32_bf16(a1[f], b0[j], acc[4 + f][j], 0, 0, 0);
    __builtin_amdgcn_s_setprio(0);
    __builtin_amdgcn_s_barrier();

#pragma unroll
    for (int f = 0; f < 4; ++f) a0[f] = rdA(Abase, 0, 1, f);
#pragma unroll
    for (int f = 0; f < 4; ++f) a1[f] = rdA(Abase, 1, 1, f);
    asm volatile("s_waitcnt lgkmcnt(0)" ::: "memory");
    __builtin_amdgcn_sched_barrier(0);
    __builtin_amdgcn_s_setprio(1);
#pragma unroll
    for (int f = 0; f < 4; ++f)
#pragma unroll
      for (int j = 0; j < 4; ++j)
        acc[f][j] = __builtin_amdgcn_mfma_f32_16x16x32_bf16(a0[f], b1[j], acc[f][j], 0, 0, 0);
    __builtin_amdgcn_s_setprio(0);
    __builtin_amdgcn_s_barrier();

    if (t < 10) stage(t + 2, c);
    __builtin_amdgcn_s_setprio(1);
#pragma unroll
    for (int f = 0; f < 4; ++f)
#pragma unroll
      for (int j = 0; j < 4; ++j)
        acc[4 + f][j] = __builtin_amdgcn_mfma_f32_16x16x32_bf16(a1[f], b1[j], acc[4 + f][j], 0, 0, 0);
    __builtin_amdgcn_s_setprio(0);
    if (t < 10) {
      asm volatile("s_waitcnt vmcnt(8)" ::: "memory");
      __builtin_amdgcn_sched_barrier(0);
      __builtin_amdgcn_s_barrier();
    } else if (t == 10) {
      asm volatile("s_waitcnt vmcnt(0)" ::: "memory");
      __builtin_amdgcn_sched_barrier(0);
      __builtin_amdgcn_s_barrier();
    }
  }

#pragma unroll
  for (int j = 0; j < 4; ++j) {
    int col = n0 + wn + j * 16 + mlane;
    float bv = bias[col];
#pragma unroll
    for (int mf = 0; mf < 8; ++mf) {
      int m = m0 + wm + (mf >> 2) * 64 + (mf & 3) * 16 + quad * 4;
#pragma unroll
      for (int r = 0; r < 4; ++r)
        out[(size_t)(m + r) * 768 + col] = acc[mf][j][r] + bv;
    }
  }
}

extern "C" void kernel_launch(void* const* d_in, const int* in_sizes, int n_in,
                              void* d_out, int out_size, void* d_ws, size_t ws_size,
                              hipStream_t stream) {
  const float* x = (const float*)d_in[0];
  const float* Wqkv = (const float*)d_in[1];
  const float* Wproj = (const float*)d_in[2];
  const float* bias = (const float*)d_in[3];
  const float* temp = (const float*)d_in[4];
  float* out = (float*)d_out;

  char* ws = (char*)d_ws;
  size_t off = 0;
  auto alloc = [&](size_t bytes) -> void* {
    void* p = ws + off;
    off += (bytes + 255) & ~(size_t)255;
    return p;
  };
  unsigned short* xb = (unsigned short*)alloc(32768ull * 768 * 2);
  unsigned short* Wtq = (unsigned short*)alloc(2304ull * 768 * 2);
  unsigned short* Wtp = (unsigned short*)alloc(768ull * 768 * 2);
  unsigned short* Qt = (unsigned short*)alloc(64ull * 96 * 4096 * 2);  // [bh][d][n]
  unsigned short* Kt = (unsigned short*)alloc(64ull * 96 * 4096 * 2);  // [bh][d][n]
  unsigned short* V = (unsigned short*)alloc(64ull * 4096 * 96 * 2);   // [bh][n][d]
  float* sq = (float*)alloc(64 * 96 * 4);
  float* sk = (float*)alloc(64 * 96 * 4);
  unsigned short* Pt = (unsigned short*)alloc(64ull * 9216 * 2);
  (void)off; (void)ws_size; (void)in_sizes; (void)n_in; (void)out_size;

  // Mt aliases xb (dead after gemm_qkv); Spart staged in d_out (written only by gemm_out).
  unsigned short* Mt = xb;
  float* Spart = out;

  static bool attr_set = false;
  if (!attr_set) {
    hipFuncSetAttribute((const void*)gemm_qkv, hipFuncAttributeMaxDynamicSharedMemorySize, 131072);
    hipFuncSetAttribute((const void*)gemm_out, hipFuncAttributeMaxDynamicSharedMemorySize, 131072);
    attr_set = true;
  }

  cvt_x<<<4096, 256, 0, stream>>>((const float4*)x, (ushort4*)xb, 32768 * 768 / 4);
  t_wqkv<<<dim3(72, 24), 256, 0, stream>>>(Wqkv, Wtq);
  t_wproj<<<dim3(24, 24), 256, 0, stream>>>(Wproj, Wtp);
  hipMemsetAsync(sq, 0, 64 * 96 * 4, stream);
  hipMemsetAsync(sk, 0, 64 * 96 * 4, stream);
  gemm_qkv<<<dim3(128, 9), 512, 131072, stream>>>(xb, Wtq, Qt, Kt, V, sq, sk);
  attn_partial<<<dim3(16, 64), 256, 0, stream>>>(Qt, Kt, Spart);
  attn_finalize<<<64, 256, 0, stream>>>(Spart, sq, sk, temp, Pt);
  m_pre<<<dim3(6, 64), 256, 0, stream>>>(Wtp, Pt, Mt);
  gemm_out<<<dim3(128, 3), 512, 131072, stream>>>(V, Mt, bias, out);
}